// Round 11
// baseline (978.182 us; speedup 1.0000x reference)
//
#include <hip/hip_runtime.h>
#include <stdint.h>

#define NU 100000
#define NI 50000
#define NBK 10
#define DD 64
#define NE 1000000
#define BATCH 2048
#define NSLICE 8
#define USLICE ((NU + NSLICE - 1) / NSLICE)   // 12500
#define ISLICE ((NI + NSLICE - 1) / NSLICE)   // 6250
#define NCHUNK 512
#define EPC ((NE + NCHUNK - 1) / NCHUNK)      // 1954
// fp8 storage scale: embeddings ~0.01 are subnormal in e4m3; x128 -> normal.
// Combined descale: (4/3 dropout) / 128 = 1/96.
#define FP8_SCALE 128.0f
#define SPMM_DESCALE (1.0f / 96.0f)
#define EL_DESCALE (1.0f / 16384.0f)   // edge-logit dot of two 128x fp8 tables
#define LOG2E5 7.2134752f              // 5*log2(e): exp(5x) = 2^(x*LOG2E5)

typedef __bf16 bf16x8 __attribute__((ext_vector_type(8)));
typedef float f32x4 __attribute__((ext_vector_type(4)));

struct Keys8 { uint32_t k[8][2]; };

// ---------------- threefry2x32 (JAX-compatible, 20 rounds) ----------------
__host__ __device__ inline void tf2x32(uint32_t k0, uint32_t k1, uint32_t x0, uint32_t x1,
                                       uint32_t& o0, uint32_t& o1) {
  uint32_t ks0 = k0, ks1 = k1, ks2 = k0 ^ k1 ^ 0x1BD11BDAu;
  x0 += ks0; x1 += ks1;
#define TFR(r) { x0 += x1; x1 = (x1 << (r)) | (x1 >> (32 - (r))); x1 ^= x0; }
  TFR(13) TFR(15) TFR(26) TFR(6)   x0 += ks1; x1 += ks2 + 1u;
  TFR(17) TFR(29) TFR(16) TFR(24)  x0 += ks2; x1 += ks0 + 2u;
  TFR(13) TFR(15) TFR(26) TFR(6)   x0 += ks0; x1 += ks1 + 3u;
  TFR(17) TFR(29) TFR(16) TFR(24)  x0 += ks1; x1 += ks2 + 4u;
  TFR(13) TFR(15) TFR(26) TFR(6)   x0 += ks2; x1 += ks0 + 5u;
#undef TFR
  o0 = x0; o1 = x1;
}

__device__ inline uint16_t f2bf(float f) {
  uint32_t u = __float_as_uint(f);
  return (uint16_t)((u + 0x7fffu + ((u >> 16) & 1u)) >> 16);   // RNE
}
__device__ inline float bf2f(uint16_t u) {
  return __uint_as_float(((uint32_t)u) << 16);
}

// ---- fp8 e4m3 (OCP) helpers ----
// byte-select must be an immediate for the builtin -> template parameter
template <int SEL>
__device__ inline float fp8_sel(uint32_t w) {
#if __has_builtin(__builtin_amdgcn_cvt_f32_fp8)
  return __builtin_amdgcn_cvt_f32_fp8((int)w, SEL);
#else
  uint32_t b = (w >> (8 * SEL)) & 0xFFu;
  uint32_t s = b >> 7, e = (b >> 3) & 0xF, m = b & 7;
  float v = (e == 0) ? (float)m * (1.0f / 512.0f)
                     : __uint_as_float(((e + 120) << 23) | (m << 20));
  return s ? -v : v;
#endif
}
__device__ inline uint32_t f32_to_fp8(float f) {
#if __has_builtin(__builtin_amdgcn_cvt_pk_fp8_f32)
  return (uint32_t)__builtin_amdgcn_cvt_pk_fp8_f32(f, f, 0, false) & 0xFFu;
#else
  uint32_t s = (__float_as_uint(f) >> 31) << 7;
  float a = fabsf(f);
  a = fminf(a, 448.0f);
  if (a < 0.015625f) {
    uint32_t m = (uint32_t)(a * 512.0f + 0.5f);
    return s | m;
  }
  int ex; float fr = frexpf(a, &ex);
  uint32_t q = (uint32_t)(fr * 16.0f + 0.5f);
  int E = ex + 6;
  if (q == 16) { q = 8; E += 1; }
  if (E > 15) { E = 15; q = 14; }
  if (E == 15 && q == 15) q = 14;
  return s | ((uint32_t)E << 3) | (q - 8);
#endif
}
__device__ inline uint32_t pack4_fp8(float a, float b, float c, float d) {
  return f32_to_fp8(a) | (f32_to_fp8(b) << 8) | (f32_to_fp8(c) << 16) | (f32_to_fp8(d) << 24);
}

__device__ inline uint32_t drop_mask(int e, uint32_t k0, uint32_t k1) {
  const uint32_t half = NE / 2;
  uint32_t lo = (e < (int)half) ? (uint32_t)e : (uint32_t)e - half;
  uint32_t o0, o1;
  tf2x32(k0, k1, lo, lo + half, o0, o1);
  uint32_t bits = (e < (int)half) ? o0 : o1;
  float u = __uint_as_float((bits >> 9) | 0x3f800000u) - 1.0f;
  return (u < 0.75f) ? 1u : 0u;
}

// dropout masks (8 bits/edge) + degree histogram, single pass over edges
__global__ void mask_hist_kernel(const int* __restrict__ rows, const int* __restrict__ cols,
                                 uint8_t* __restrict__ mask,
                                 int* __restrict__ cntU, int* __restrict__ cntI, Keys8 K) {
  int e = blockIdx.x * blockDim.x + threadIdx.x;
  if (e >= NE) return;
  uint32_t m = 0;
#pragma unroll
  for (int j = 0; j < 8; ++j) m |= drop_mask(e, K.k[j][0], K.k[j][1]) << j;
  mask[e] = (uint8_t)m;
  atomicAdd(&cntU[rows[e]], 1);
  atomicAdd(&cntI[cols[e]], 1);
}

#define SCAN_B 256
__global__ void scan_phase1(const int* __restrict__ cntU, const int* __restrict__ cntI,
                            int nbU, int* __restrict__ bs) {
  __shared__ int red[SCAN_B];
  int blk = blockIdx.x, t = threadIdx.x;
  const int* cnt; int n, j;
  if (blk < nbU) { cnt = cntU; n = NU; j = blk; }
  else { cnt = cntI; n = NI; j = blk - nbU; }
  int i = j * SCAN_B + t;
  red[t] = (i < n) ? cnt[i] : 0;
  __syncthreads();
  for (int s = 128; s > 0; s >>= 1) {
    if (t < s) red[t] += red[t + s];
    __syncthreads();
  }
  if (t == 0) bs[blk] = red[0];
}
__global__ void scan_phase2(int* __restrict__ bs, int nbU, int nbI) {
  __shared__ int sh[512];
  int t = threadIdx.x;
  int v = (t < nbU) ? bs[t] : 0;
  sh[t] = v;
  __syncthreads();
  for (int off = 1; off < 512; off <<= 1) {
    int add = (t >= off) ? sh[t - off] : 0;
    __syncthreads();
    sh[t] += add;
    __syncthreads();
  }
  if (t < nbU) bs[t] = sh[t] - v;
  __syncthreads();
  int v2 = (t < nbI) ? bs[nbU + t] : 0;
  sh[t] = v2;
  __syncthreads();
  for (int off = 1; off < 512; off <<= 1) {
    int add = (t >= off) ? sh[t - off] : 0;
    __syncthreads();
    sh[t] += add;
    __syncthreads();
  }
  if (t < nbI) bs[nbU + t] = sh[t] - v2;
}
__global__ void scan_phase3(const int* __restrict__ cntU, const int* __restrict__ cntI,
                            int nbU, const int* __restrict__ bs,
                            int* __restrict__ offU, int* __restrict__ offI) {
  __shared__ int sh[SCAN_B];
  int blk = blockIdx.x, t = threadIdx.x;
  const int* cnt; int n, j; int* off;
  if (blk < nbU) { cnt = cntU; n = NU; j = blk; off = offU; }
  else { cnt = cntI; n = NI; j = blk - nbU; off = offI; }
  int i = j * SCAN_B + t;
  int v = (i < n) ? cnt[i] : 0;
  sh[t] = v;
  __syncthreads();
  for (int o = 1; o < SCAN_B; o <<= 1) {
    int add = (t >= o) ? sh[t - o] : 0;
    __syncthreads();
    sh[t] += add;
    __syncthreads();
  }
  if (i < n) off[i] = bs[blk] + sh[t] - v;
  if (i == n - 1) off[n] = bs[blk] + sh[t];
}

// XCD-sliced scatter (slice = blockIdx&7): each output slice dirtied by one XCD.
__global__ __launch_bounds__(256)
void scatter_kernel(const int* __restrict__ rows, const int* __restrict__ cols,
                    const uint8_t* __restrict__ mask,
                    const int* __restrict__ offU, const int* __restrict__ offI,
                    int* __restrict__ fillU, int* __restrict__ fillI,
                    int2* __restrict__ cpU, int2* __restrict__ cpI) {
  int slice = blockIdx.x & 7;
  int chunk = blockIdx.x >> 3;
  int base = chunk * EPC;
  int end = base + EPC; if (end > NE) end = NE;
  for (int e = base + threadIdx.x; e < end; e += 256) {
    int r = rows[e], c = cols[e];
    uint32_t m = mask[e];
    if (r / USLICE == slice) {
      int packed = c | (int)((m & 0xFu) << 17);
      int pu = offU[r] + atomicAdd(&fillU[r], 1);
      cpU[pu] = make_int2(packed, e);
    }
    if (c / ISLICE == slice) {
      int packed = r | (int)(((m >> 4) & 0xFu) << 17);
      int pi = offI[c] + atomicAdd(&fillI[c], 1);
      cpI[pi] = make_int2(packed, e);
    }
  }
}

// merged U+I gather-reduce SpMM, sub-wave layout: wave = 4 rows x 16 lanes,
// lane covers 4 dims via one dword fp8 load (cvt_f32_fp8 byte-select).
// layer0 (base!=null): d8 = fp8(raw*4/3), sum = bf16(base + raw/96)
// layer1: sum += raw/96 (bf16 RMW); optional fp8(sum*128) table out (s8*).
__global__ __launch_bounds__(256)
void spmm_layer_kernel(const int* __restrict__ offU, const int2* __restrict__ cpU,
                       const int* __restrict__ offI, const int2* __restrict__ cpI,
                       const float* __restrict__ esrc, int shift,
                       const uint8_t* __restrict__ SU, const uint8_t* __restrict__ SI,
                       uint8_t* __restrict__ dU, uint8_t* __restrict__ dI,
                       uint16_t* __restrict__ sumU, uint16_t* __restrict__ sumI,
                       const float* __restrict__ baseU, const float* __restrict__ baseI,
                       uint8_t* __restrict__ s8U, uint8_t* __restrict__ s8I) {
  int lane = threadIdx.x & 63;
  int g = lane >> 4, l15 = lane & 15;
  int w = (blockIdx.x * blockDim.x + threadIdx.x) >> 6;
  int r = w * 4 + g;                       // NU%4==0 -> wave never straddles U/I
  const int* off; const int2* cp; const uint8_t* S;
  uint8_t* D; uint16_t* Sum; const float* base; uint8_t* S8; int row;
  if (r < NU) {
    row = r; off = offU; cp = cpU; S = SU; D = dU; Sum = sumU; base = baseU; S8 = s8U;
  } else {
    row = r - NU; off = offI; cp = cpI; S = SI; D = dI; Sum = sumI; base = baseI; S8 = s8I;
  }
  int p0 = off[row], p1 = off[row + 1];
  f32x4 acc = {0.f, 0.f, 0.f, 0.f};
  int p = p0;
  for (; p + 2 <= p1; p += 2) {            // 2 gathers in flight per group
    int2 c0 = cp[p], c1 = cp[p + 1];
    uint32_t w0 = *(const uint32_t*)(S + ((size_t)(uint32_t)(c0.x & 0x1FFFF) << 6) + l15 * 4);
    uint32_t w1 = *(const uint32_t*)(S + ((size_t)(uint32_t)(c1.x & 0x1FFFF) << 6) + l15 * 4);
    float v0 = esrc[c0.y] * (float)((c0.x >> shift) & 1);
    float v1 = esrc[c1.y] * (float)((c1.x >> shift) & 1);
    acc[0] += v0 * fp8_sel<0>(w0) + v1 * fp8_sel<0>(w1);
    acc[1] += v0 * fp8_sel<1>(w0) + v1 * fp8_sel<1>(w1);
    acc[2] += v0 * fp8_sel<2>(w0) + v1 * fp8_sel<2>(w1);
    acc[3] += v0 * fp8_sel<3>(w0) + v1 * fp8_sel<3>(w1);
  }
  if (p < p1) {
    int2 c0 = cp[p];
    float v0 = esrc[c0.y] * (float)((c0.x >> shift) & 1);
    if (v0 != 0.f) {
      uint32_t w0 = *(const uint32_t*)(S + ((size_t)(uint32_t)(c0.x & 0x1FFFF) << 6) + l15 * 4);
      acc[0] += v0 * fp8_sel<0>(w0);
      acc[1] += v0 * fp8_sel<1>(w0);
      acc[2] += v0 * fp8_sel<2>(w0);
      acc[3] += v0 * fp8_sel<3>(w0);
    }
  }
  size_t idx = (size_t)row * DD + l15 * 4;
  if (D) {
    *(uint32_t*)(D + idx) = pack4_fp8(acc[0] * (4.0f / 3.0f), acc[1] * (4.0f / 3.0f),
                                      acc[2] * (4.0f / 3.0f), acc[3] * (4.0f / 3.0f));
    float4 b4 = *(const float4*)(base + idx);
    ushort4 s;
    s.x = f2bf(b4.x + acc[0] * SPMM_DESCALE);
    s.y = f2bf(b4.y + acc[1] * SPMM_DESCALE);
    s.z = f2bf(b4.z + acc[2] * SPMM_DESCALE);
    s.w = f2bf(b4.w + acc[3] * SPMM_DESCALE);
    *(ushort4*)(Sum + idx) = s;
  } else {
    ushort4 s = *(const ushort4*)(Sum + idx);
    float s0 = bf2f(s.x) + acc[0] * SPMM_DESCALE;
    float s1 = bf2f(s.y) + acc[1] * SPMM_DESCALE;
    float s2 = bf2f(s.z) + acc[2] * SPMM_DESCALE;
    float s3 = bf2f(s.w) + acc[3] * SPMM_DESCALE;
    s.x = f2bf(s0); s.y = f2bf(s1); s.z = f2bf(s2); s.w = f2bf(s3);
    *(ushort4*)(Sum + idx) = s;
    if (S8)
      *(uint32_t*)(S8 + idx) = pack4_fp8(s0 * FP8_SCALE, s1 * FP8_SCALE,
                                         s2 * FP8_SCALE, s3 * FP8_SCALE);
  }
}

// 4 edges per wave (16 lanes x 4 dims), fp8 sum tables (64B rows)
__global__ void edge_logit_kernel(const uint8_t* __restrict__ E8u,
                                  const uint8_t* __restrict__ E8i,
                                  const int* __restrict__ rows, const int* __restrict__ cols,
                                  const float* __restrict__ av, float* __restrict__ aug) {
  int lane = threadIdx.x & 63;
  int sub = lane >> 4, l15 = lane & 15;
  int w = (blockIdx.x * blockDim.x + threadIdx.x) >> 6;
  int nw = (gridDim.x * blockDim.x) >> 6;
  for (int b = w * 4; b < NE; b += nw * 4) {
    int e = b + sub;
    uint32_t wa = *(const uint32_t*)(E8u + ((size_t)rows[e] << 6) + l15 * 4);
    uint32_t wc = *(const uint32_t*)(E8i + ((size_t)cols[e] << 6) + l15 * 4);
    float p = fp8_sel<0>(wa) * fp8_sel<0>(wc) + fp8_sel<1>(wa) * fp8_sel<1>(wc) +
              fp8_sel<2>(wa) * fp8_sel<2>(wc) + fp8_sel<3>(wa) * fp8_sel<3>(wc);
#pragma unroll
    for (int off = 8; off > 0; off >>= 1) p += __shfl_down(p, off, 16);
    if (l15 == 0) aug[e] = av[e] / (1.0f + __expf(-p * EL_DESCALE));
  }
}

// both base tables fp32 -> fp8(x128) in one launch, 4 elems/thread
__global__ void cvt2_fp8_kernel(const float4* __restrict__ a, int na4, uint32_t* __restrict__ oa,
                                const float4* __restrict__ b, int nb4, uint32_t* __restrict__ ob) {
  int total = na4 + nb4;
  for (int i = blockIdx.x * blockDim.x + threadIdx.x; i < total; i += gridDim.x * blockDim.x) {
    float4 v = (i < na4) ? a[i] : b[i - na4];
    uint32_t w = pack4_fp8(v.x * FP8_SCALE, v.y * FP8_SCALE, v.z * FP8_SCALE, v.w * FP8_SCALE);
    if (i < na4) oa[i] = w; else ob[i - na4] = w;
  }
}

// gather both Z row sets; PRE-SCALE by LOG2E5 so PCL's MFMA emits
// already-log2-scaled logits (removes one fma per C element in the hot loop)
__global__ void gather2_rows_kernel(const uint16_t* __restrict__ Z16u, const int* __restrict__ uids,
                                    uint16_t* __restrict__ ou,
                                    const uint16_t* __restrict__ Z16i, const int* __restrict__ iids,
                                    uint16_t* __restrict__ oi) {
  int b = blockIdx.x, lane = threadIdx.x;
  if (b < BATCH)
    ou[(size_t)b * 64 + lane] = f2bf(bf2f(Z16u[(size_t)uids[b] * 64 + lane]) * LOG2E5);
  else {
    int bb = b - BATCH;
    oi[(size_t)bb * 64 + lane] = f2bf(bf2f(Z16i[(size_t)iids[bb] * 64 + lane]) * LOG2E5);
  }
}

// PCL denominator: S[m] += sum_n exp2(dot(Zg_scaled[m],E[n])), bf16 MFMA.
// Wave pins A-frags for EIGHT m-tiles (128 m-rows); A pre-scaled by LOG2E5.
__global__ __launch_bounds__(256)
void pcl_mfma4_kernel(const uint16_t* __restrict__ Zg, const uint16_t* __restrict__ E16,
                      int NT, int SPL, float* __restrict__ S) {
  int lane = threadIdx.x & 63;
  int wave = threadIdx.x >> 6;
  int quad = lane >> 4, l15 = lane & 15;
  int mt0 = (blockIdx.y * 4 + wave) * 8;       // 8 consecutive m-tiles per wave
  bf16x8 a0[8], a1[8];
#pragma unroll
  for (int i = 0; i < 8; ++i) {
    const uint16_t* ar = Zg + (size_t)((mt0 + i) * 16 + l15) * 64 + quad * 8;
    a0[i] = *(const bf16x8*)ar;
    a1[i] = *(const bf16x8*)(ar + 32);
  }
  f32x4 rs[8] = {};
  int nt = blockIdx.x;
  bf16x8 b0 = {}, b1 = {};
  if (nt < NT) {
    const uint16_t* br = E16 + (size_t)(nt * 16 + l15) * 64 + quad * 8;
    b0 = *(const bf16x8*)br;
    b1 = *(const bf16x8*)(br + 32);
  }
  while (nt < NT) {
    int nn = nt + SPL;
    bf16x8 p0 = {}, p1 = {};
    if (nn < NT) {
      const uint16_t* pr = E16 + (size_t)(nn * 16 + l15) * 64 + quad * 8;
      p0 = *(const bf16x8*)pr;
      p1 = *(const bf16x8*)(pr + 32);
    }
#pragma unroll
    for (int i = 0; i < 8; ++i) {
      f32x4 c = {0.f, 0.f, 0.f, 0.f};
      c = __builtin_amdgcn_mfma_f32_16x16x32_bf16(a0[i], b0, c, 0, 0, 0);
      c = __builtin_amdgcn_mfma_f32_16x16x32_bf16(a1[i], b1, c, 0, 0, 0);
#pragma unroll
      for (int r = 0; r < 4; ++r) rs[i][r] += __builtin_amdgcn_exp2f(c[r]);
    }
    b0 = p0; b1 = p1; nt = nn;
  }
#pragma unroll
  for (int off = 8; off > 0; off >>= 1) {
#pragma unroll
    for (int i = 0; i < 8; ++i)
#pragma unroll
      for (int r = 0; r < 4; ++r) rs[i][r] += __shfl_down(rs[i][r], off, 16);
  }
  if (l15 == 0) {
#pragma unroll
    for (int i = 0; i < 8; ++i)
#pragma unroll
      for (int r = 0; r < 4; ++r)
        atomicAdd(&S[(mt0 + i) * 16 + quad * 4 + r], rs[i][r]);
  }
}

__global__ void bpr_kernel(const uint16_t* __restrict__ E16u, const uint16_t* __restrict__ E16i,
                           const int* __restrict__ uids, const int* __restrict__ pos,
                           const int* __restrict__ neg, float* __restrict__ ps,
                           float* __restrict__ acc) {
  int lane = threadIdx.x & 63;
  int b = (blockIdx.x * blockDim.x + threadIdx.x) >> 6;
  if (b >= BATCH) return;
  float u = bf2f(E16u[(size_t)uids[b] * DD + lane]);
  float p = u * bf2f(E16i[(size_t)pos[b] * DD + lane]);
  float n = u * bf2f(E16i[(size_t)neg[b] * DD + lane]);
#pragma unroll
  for (int off = 32; off > 0; off >>= 1) { p += __shfl_down(p, off); n += __shfl_down(n, off); }
  if (lane == 0) {
    ps[b] = p;
    float x = p - n;
    atomicAdd(&acc[0], logf(1.0f / (1.0f + __expf(-x))));
  }
}

__global__ void minmax_kernel(const float* __restrict__ ps, float* __restrict__ mm) {
  __shared__ float smn[256], smx[256];
  int tid = threadIdx.x;
  float mn = 3.0e38f, mx = -3.0e38f;
  for (int i = tid; i < BATCH; i += 256) { float v = ps[i]; mn = fminf(mn, v); mx = fmaxf(mx, v); }
  smn[tid] = mn; smx[tid] = mx;
  __syncthreads();
  for (int s = 128; s > 0; s >>= 1) {
    if (tid < s) { smn[tid] = fminf(smn[tid], smn[tid + s]); smx[tid] = fmaxf(smx[tid], smx[tid + s]); }
    __syncthreads();
  }
  if (tid == 0) { mm[0] = smn[0]; mm[1] = smx[0]; }
}

__global__ void bcl_kernel(const uint16_t* __restrict__ E16u, const uint16_t* __restrict__ E16i,
                           const float* __restrict__ Eb, const int* __restrict__ uids,
                           const int* __restrict__ pos, const float* __restrict__ ps,
                           const float* __restrict__ mm, float* __restrict__ acc) {
  int lane = threadIdx.x & 63;
  int b = (blockIdx.x * blockDim.x + threadIdx.x) >> 6;
  if (b >= BATCH) return;
  float wgt = (ps[b] - mm[0]) / (mm[1] - mm[0] + 1e-9f);
  int rel = (int)(wgt * 10.0f);
  rel = rel < 0 ? 0 : (rel > 9 ? 9 : rel);
  float x = bf2f(E16u[(size_t)uids[b] * DD + lane]) * bf2f(E16i[(size_t)pos[b] * DD + lane]);
  float el = 1.0f / (1.0f + __expf(-x));
  float sneg = 0.f, spos = 0.f;
  for (int k = 0; k < NBK; ++k) {
    float d = el * Eb[k * DD + lane];
#pragma unroll
    for (int off = 32; off > 0; off >>= 1) d += __shfl_down(d, off);
    if (lane == 0) { if (k == rel) spos = d; else sneg += d; }
  }
  if (lane == 0) {
    atomicAdd(&acc[5], sneg * 0.1f);
    atomicAdd(&acc[6], spos);
  }
}

__global__ void pclpos2_kernel(const uint16_t* __restrict__ Z16u, const uint16_t* __restrict__ E16u,
                               const int* __restrict__ uids,
                               const uint16_t* __restrict__ Z16i, const uint16_t* __restrict__ E16i,
                               const int* __restrict__ iids, float* __restrict__ acc) {
  int lane = threadIdx.x & 63;
  int b = (blockIdx.x * blockDim.x + threadIdx.x) >> 6;
  if (b >= 2 * BATCH) return;
  const uint16_t *Z, *E; const int* ids; int idx, bb;
  if (b < BATCH) { Z = Z16u; E = E16u; ids = uids; idx = 3; bb = b; }
  else { Z = Z16i; E = E16i; ids = iids; idx = 4; bb = b - BATCH; }
  size_t r = (size_t)ids[bb] * DD + lane;
  float p = bf2f(Z[r]) * bf2f(E[r]);
#pragma unroll
  for (int off = 32; off > 0; off >>= 1) p += __shfl_down(p, off);
  if (lane == 0) {
    float x = p * 5.0f;
    x = fminf(5.0f, fmaxf(-5.0f, x));
    atomicAdd(&acc[idx], x);
  }
}

__global__ void sumsq3_kernel(const float* __restrict__ a, int na,
                              const float* __restrict__ b, int nb,
                              const float* __restrict__ c, int nc,
                              float* __restrict__ acc) {
  __shared__ float red[256];
  int tid = threadIdx.x;
  int total = na + nb + nc;
  float s = 0.f;
  for (int i = blockIdx.x * blockDim.x + tid; i < total; i += gridDim.x * blockDim.x) {
    float v = (i < na) ? a[i] : (i < na + nb) ? b[i - na] : c[i - na - nb];
    s += v * v;
  }
  red[tid] = s;
  __syncthreads();
  for (int st = 128; st > 0; st >>= 1) {
    if (tid < st) red[tid] += red[tid + st];
    __syncthreads();
  }
  if (tid == 0) atomicAdd(&acc[7], red[0]);
}

__global__ void finalize_kernel(const float* __restrict__ Su, const float* __restrict__ Si,
                                const float* __restrict__ acc, float* __restrict__ out) {
  __shared__ float r1[256], r2[256];
  int tid = threadIdx.x;
  float su = 0.f, si = 0.f;
  for (int b = tid; b < BATCH; b += 256) {
    su += logf(Su[b] + 1e-8f);
    si += logf(Si[b] + 1e-8f);
  }
  r1[tid] = su; r2[tid] = si;
  __syncthreads();
  for (int s = 128; s > 0; s >>= 1) {
    if (tid < s) { r1[tid] += r1[tid + s]; r2[tid] += r2[tid + s]; }
    __syncthreads();
  }
  if (tid == 0) {
    const float inv = 1.0f / (float)BATCH;
    float neg_s = (r1[0] + r2[0]) * inv;
    float pos_s = (acc[3] + acc[4]) * inv;
    float pcl = neg_s - pos_s;
    float bpr = -acc[0] * inv;
    float bcl = (acc[5] - acc[6]) * inv;
    float reg = 1e-7f * acc[7];
    float loss = bpr + 0.2f * pcl + 0.2f * bcl + reg;
    out[0] = loss; out[1] = bpr; out[2] = 0.2f * pcl; out[3] = 0.2f * bcl;
  }
}

extern "C" void kernel_launch(void* const* d_in, const int* in_sizes, int n_in,
                              void* d_out, int out_size, void* d_ws, size_t ws_size,
                              hipStream_t stream) {
  (void)in_sizes; (void)n_in; (void)out_size; (void)ws_size;
  const float* Eu0 = (const float*)d_in[0];
  const float* Ev0 = (const float*)d_in[1];
  const float* Eb  = (const float*)d_in[2];
  const float* av  = (const float*)d_in[3];
  const int* rows  = (const int*)d_in[4];
  const int* cols  = (const int*)d_in[5];
  const int* uids  = (const int*)d_in[6];
  const int* iids  = (const int*)d_in[7];
  const int* pos   = (const int*)d_in[8];
  const int* neg   = (const int*)d_in[9];
  float* out = (float*)d_out;

  float* w = (float*)d_ws;
  size_t o = 0;
  float* augv = w + o; o += NE;
  float* ps  = w + o; o += BATCH;
  float* Su  = w + o; o += BATCH;
  float* Si  = w + o; o += BATCH;
  float* acc = w + o; o += 16;
  float* mm  = w + o; o += 2;
  // bf16 running-sum tables + gathered Z rows
  uint16_t* hp = (uint16_t*)(w + o);
  uint16_t* E16u = hp; hp += (size_t)NU * DD;
  uint16_t* E16i = hp; hp += (size_t)NI * DD;
  uint16_t* Z16u = hp; hp += (size_t)NU * DD;
  uint16_t* Z16i = hp; hp += (size_t)NI * DD;
  uint16_t* Zgu  = hp; hp += (size_t)BATCH * DD;
  uint16_t* Zgi  = hp; hp += (size_t)BATCH * DD;
  // fp8 tables
  uint8_t* bp = (uint8_t*)hp;
  uint8_t* E0u8 = bp; bp += (size_t)NU * DD;    // fp8(128*Eu0)
  uint8_t* E0v8 = bp; bp += (size_t)NI * DD;
  uint8_t* d8U  = bp; bp += (size_t)NU * DD;    // layer0 outs (fp8, 128x)
  uint8_t* d8I  = bp; bp += (size_t)NI * DD;
  uint8_t* E8su = bp; bp += (size_t)NU * DD;    // fp8(128*E_u sums) for edge_logit
  uint8_t* E8si = bp; bp += (size_t)NI * DD;
  uint8_t* mask8 = bp; bp += NE;
  // int region (8B aligned)
  int* ip = (int*)(((uintptr_t)bp + 7) & ~(uintptr_t)7);
  int* offU = ip; ip += NU + 1;
  int* offI = ip; ip += NI + 1;
  int* cntU = ip; ip += NU;
  int* cntI = ip; ip += NI;
  ip += 2;
  int2* cpU = (int2*)ip; ip += 2 * (size_t)NE;
  int2* cpI = (int2*)ip; ip += 2 * (size_t)NE;

  // key chain: key(42) = (0,42); fold_in(k,d) = threefry2x32(k, [0,d])
  uint32_t bk[2][2];
  tf2x32(0u, 42u, 0u, 0u, bk[0][0], bk[0][1]);
  tf2x32(0u, 42u, 0u, 1u, bk[1][0], bk[1][1]);
  Keys8 K;
  for (int p = 0; p < 2; ++p)
    for (int l = 0; l < 2; ++l) {
      tf2x32(bk[p][0], bk[p][1], 0u, (uint32_t)(2 * l),     K.k[p * 2 + l][0], K.k[p * 2 + l][1]);
      tf2x32(bk[p][0], bk[p][1], 0u, (uint32_t)(2 * l + 1), K.k[4 + p * 2 + l][0], K.k[4 + p * 2 + l][1]);
    }

  const int EB = (NE + 255) / 256;
  const int nbU = (NU + SCAN_B - 1) / SCAN_B;
  const int nbI = (NI + SCAN_B - 1) / SCAN_B;

  cvt2_fp8_kernel<<<2048, 256, 0, stream>>>((const float4*)Eu0, NU * DD / 4, (uint32_t*)E0u8,
                                            (const float4*)Ev0, NI * DD / 4, (uint32_t*)E0v8);
  (void)hipMemsetAsync(cntU, 0, (size_t)(NU + NI) * sizeof(int), stream);
  mask_hist_kernel<<<EB, 256, 0, stream>>>(rows, cols, mask8, cntU, cntI, K);
  {
    int* bs = (int*)cpU;
    scan_phase1<<<nbU + nbI, SCAN_B, 0, stream>>>(cntU, cntI, nbU, bs);
    scan_phase2<<<1, 512, 0, stream>>>(bs, nbU, nbI);
    scan_phase3<<<nbU + nbI, SCAN_B, 0, stream>>>(cntU, cntI, nbU, bs, offU, offI);
  }
  (void)hipMemsetAsync(cntU, 0, (size_t)(NU + NI) * sizeof(int), stream);
  scatter_kernel<<<NCHUNK * NSLICE, 256, 0, stream>>>(rows, cols, mask8, offU, offI,
                                                      cntU, cntI, cpU, cpI);

  const int SPB = (NU + NI) / 16;   // 4 rows/wave, 4 waves/block -> 9375 blocks

  // ---- propagation 0 (mask bits 17/18) -> E16u/E16i (+fp8 sums) ----
  spmm_layer_kernel<<<SPB, 256, 0, stream>>>(offU, cpU, offI, cpI, av, 17,
                                             E0v8, E0u8, d8U, d8I,
                                             E16u, E16i, Eu0, Ev0, nullptr, nullptr);
  spmm_layer_kernel<<<SPB, 256, 0, stream>>>(offU, cpU, offI, cpI, av, 18,
                                             d8I, d8U, nullptr, nullptr,
                                             E16u, E16i, nullptr, nullptr, E8su, E8si);

  edge_logit_kernel<<<4096, 256, 0, stream>>>(E8su, E8si, rows, cols, av, augv);

  // ---- propagation 1 (mask bits 19/20) -> Z16u/Z16i ----
  spmm_layer_kernel<<<SPB, 256, 0, stream>>>(offU, cpU, offI, cpI, augv, 19,
                                             E0v8, E0u8, d8U, d8I,
                                             Z16u, Z16i, Eu0, Ev0, nullptr, nullptr);
  spmm_layer_kernel<<<SPB, 256, 0, stream>>>(offU, cpU, offI, cpI, augv, 20,
                                             d8I, d8U, nullptr, nullptr,
                                             Z16u, Z16i, nullptr, nullptr, nullptr, nullptr);

  gather2_rows_kernel<<<2 * BATCH, 64, 0, stream>>>(Z16u, uids, Zgu, Z16i, iids, Zgi);

  (void)hipMemsetAsync(Su, 0, (2 * BATCH + 16) * sizeof(float), stream);

  bpr_kernel<<<BATCH / 4, 256, 0, stream>>>(E16u, E16i, uids, pos, neg, ps, acc);
  minmax_kernel<<<1, 256, 0, stream>>>(ps, mm);
  bcl_kernel<<<BATCH / 4, 256, 0, stream>>>(E16u, E16i, Eb, uids, pos, ps, mm, acc);

  // PCL denominators: wave = 8 m-tiles; grid y=4 (128 m-tiles), x = n-splits
  // 2x grid vs round-10: 8 blocks/CU dispatched (6 resident at VGPR=80)
  pcl_mfma4_kernel<<<dim3(512, 4), 256, 0, stream>>>(Zgu, E16u, NU / 16, 512, Su);
  pcl_mfma4_kernel<<<dim3(256, 4), 256, 0, stream>>>(Zgi, E16i, NI / 16, 256, Si);

  pclpos2_kernel<<<2 * BATCH / 4, 256, 0, stream>>>(Z16u, E16u, uids, Z16i, E16i, iids, acc);

  sumsq3_kernel<<<1024, 256, 0, stream>>>(Eu0, NU * DD, Ev0, NI * DD, Eb, NBK * DD, acc);

  finalize_kernel<<<1, 256, 0, stream>>>(Su, Si, acc, out);
}

// Round 12
// 897.866 us; speedup vs baseline: 1.0895x; 1.0895x over previous
//
#include <hip/hip_runtime.h>
#include <stdint.h>

#define NU 100000
#define NI 50000
#define NBK 10
#define DD 64
#define NE 1000000
#define BATCH 2048
#define NSLICE 8
#define USLICE ((NU + NSLICE - 1) / NSLICE)   // 12500
#define ISLICE ((NI + NSLICE - 1) / NSLICE)   // 6250
#define NCHUNK 512
#define EPC ((NE + NCHUNK - 1) / NCHUNK)      // 1954
// fp8 storage scale: embeddings ~0.01 are subnormal in e4m3; x128 -> normal.
// Combined descale: (4/3 dropout) / 128 = 1/96.
#define FP8_SCALE 128.0f
#define SPMM_DESCALE (1.0f / 96.0f)
#define EL_DESCALE (1.0f / 16384.0f)   // edge-logit dot of two 128x fp8 tables
#define LOG2E5 7.2134752f              // 5*log2(e): exp(5x) = 2^(x*LOG2E5)

typedef __bf16 bf16x8 __attribute__((ext_vector_type(8)));
typedef float f32x4 __attribute__((ext_vector_type(4)));

struct Keys8 { uint32_t k[8][2]; };

// ---------------- threefry2x32 (JAX-compatible, 20 rounds) ----------------
__host__ __device__ inline void tf2x32(uint32_t k0, uint32_t k1, uint32_t x0, uint32_t x1,
                                       uint32_t& o0, uint32_t& o1) {
  uint32_t ks0 = k0, ks1 = k1, ks2 = k0 ^ k1 ^ 0x1BD11BDAu;
  x0 += ks0; x1 += ks1;
#define TFR(r) { x0 += x1; x1 = (x1 << (r)) | (x1 >> (32 - (r))); x1 ^= x0; }
  TFR(13) TFR(15) TFR(26) TFR(6)   x0 += ks1; x1 += ks2 + 1u;
  TFR(17) TFR(29) TFR(16) TFR(24)  x0 += ks2; x1 += ks0 + 2u;
  TFR(13) TFR(15) TFR(26) TFR(6)   x0 += ks0; x1 += ks1 + 3u;
  TFR(17) TFR(29) TFR(16) TFR(24)  x0 += ks1; x1 += ks2 + 4u;
  TFR(13) TFR(15) TFR(26) TFR(6)   x0 += ks2; x1 += ks0 + 5u;
#undef TFR
  o0 = x0; o1 = x1;
}

__device__ inline uint16_t f2bf(float f) {
  uint32_t u = __float_as_uint(f);
  return (uint16_t)((u + 0x7fffu + ((u >> 16) & 1u)) >> 16);   // RNE
}
__device__ inline float bf2f(uint16_t u) {
  return __uint_as_float(((uint32_t)u) << 16);
}

// ---- fp8 e4m3 (OCP) helpers ----
// byte-select must be an immediate for the builtin -> template parameter
template <int SEL>
__device__ inline float fp8_sel(uint32_t w) {
#if __has_builtin(__builtin_amdgcn_cvt_f32_fp8)
  return __builtin_amdgcn_cvt_f32_fp8((int)w, SEL);
#else
  uint32_t b = (w >> (8 * SEL)) & 0xFFu;
  uint32_t s = b >> 7, e = (b >> 3) & 0xF, m = b & 7;
  float v = (e == 0) ? (float)m * (1.0f / 512.0f)
                     : __uint_as_float(((e + 120) << 23) | (m << 20));
  return s ? -v : v;
#endif
}
__device__ inline uint32_t f32_to_fp8(float f) {
#if __has_builtin(__builtin_amdgcn_cvt_pk_fp8_f32)
  return (uint32_t)__builtin_amdgcn_cvt_pk_fp8_f32(f, f, 0, false) & 0xFFu;
#else
  uint32_t s = (__float_as_uint(f) >> 31) << 7;
  float a = fabsf(f);
  a = fminf(a, 448.0f);
  if (a < 0.015625f) {
    uint32_t m = (uint32_t)(a * 512.0f + 0.5f);
    return s | m;
  }
  int ex; float fr = frexpf(a, &ex);
  uint32_t q = (uint32_t)(fr * 16.0f + 0.5f);
  int E = ex + 6;
  if (q == 16) { q = 8; E += 1; }
  if (E > 15) { E = 15; q = 14; }
  if (E == 15 && q == 15) q = 14;
  return s | ((uint32_t)E << 3) | (q - 8);
#endif
}
__device__ inline uint32_t pack4_fp8(float a, float b, float c, float d) {
  return f32_to_fp8(a) | (f32_to_fp8(b) << 8) | (f32_to_fp8(c) << 16) | (f32_to_fp8(d) << 24);
}

// dropout masks for edge pair (e, e+half) from ONE threefry eval per key:
// o0 -> element e, o1 -> element e+half (JAX split-iota semantics).
// Also accumulates the degree histogram for both edges.
__global__ void mask_hist_kernel(const int* __restrict__ rows, const int* __restrict__ cols,
                                 uint8_t* __restrict__ mask,
                                 int* __restrict__ cntU, int* __restrict__ cntI, Keys8 K) {
  const int half = NE / 2;
  int e = blockIdx.x * blockDim.x + threadIdx.x;
  if (e >= half) return;
  uint32_t mlo = 0, mhi = 0;
#pragma unroll
  for (int j = 0; j < 8; ++j) {
    uint32_t o0, o1;
    tf2x32(K.k[j][0], K.k[j][1], (uint32_t)e, (uint32_t)(e + half), o0, o1);
    float u0 = __uint_as_float((o0 >> 9) | 0x3f800000u) - 1.0f;
    float u1 = __uint_as_float((o1 >> 9) | 0x3f800000u) - 1.0f;
    mlo |= (u0 < 0.75f ? 1u : 0u) << j;
    mhi |= (u1 < 0.75f ? 1u : 0u) << j;
  }
  mask[e] = (uint8_t)mlo;
  mask[e + half] = (uint8_t)mhi;
  atomicAdd(&cntU[rows[e]], 1);
  atomicAdd(&cntI[cols[e]], 1);
  atomicAdd(&cntU[rows[e + half]], 1);
  atomicAdd(&cntI[cols[e + half]], 1);
}

#define SCAN_B 256
__global__ void scan_phase1(const int* __restrict__ cntU, const int* __restrict__ cntI,
                            int nbU, int* __restrict__ bs) {
  __shared__ int red[SCAN_B];
  int blk = blockIdx.x, t = threadIdx.x;
  const int* cnt; int n, j;
  if (blk < nbU) { cnt = cntU; n = NU; j = blk; }
  else { cnt = cntI; n = NI; j = blk - nbU; }
  int i = j * SCAN_B + t;
  red[t] = (i < n) ? cnt[i] : 0;
  __syncthreads();
  for (int s = 128; s > 0; s >>= 1) {
    if (t < s) red[t] += red[t + s];
    __syncthreads();
  }
  if (t == 0) bs[blk] = red[0];
}
__global__ void scan_phase2(int* __restrict__ bs, int nbU, int nbI) {
  __shared__ int sh[512];
  int t = threadIdx.x;
  int v = (t < nbU) ? bs[t] : 0;
  sh[t] = v;
  __syncthreads();
  for (int off = 1; off < 512; off <<= 1) {
    int add = (t >= off) ? sh[t - off] : 0;
    __syncthreads();
    sh[t] += add;
    __syncthreads();
  }
  if (t < nbU) bs[t] = sh[t] - v;
  __syncthreads();
  int v2 = (t < nbI) ? bs[nbU + t] : 0;
  sh[t] = v2;
  __syncthreads();
  for (int off = 1; off < 512; off <<= 1) {
    int add = (t >= off) ? sh[t - off] : 0;
    __syncthreads();
    sh[t] += add;
    __syncthreads();
  }
  if (t < nbI) bs[nbU + t] = sh[t] - v2;
}
__global__ void scan_phase3(const int* __restrict__ cntU, const int* __restrict__ cntI,
                            int nbU, const int* __restrict__ bs,
                            int* __restrict__ offU, int* __restrict__ offI) {
  __shared__ int sh[SCAN_B];
  int blk = blockIdx.x, t = threadIdx.x;
  const int* cnt; int n, j; int* off;
  if (blk < nbU) { cnt = cntU; n = NU; j = blk; off = offU; }
  else { cnt = cntI; n = NI; j = blk - nbU; off = offI; }
  int i = j * SCAN_B + t;
  int v = (i < n) ? cnt[i] : 0;
  sh[t] = v;
  __syncthreads();
  for (int o = 1; o < SCAN_B; o <<= 1) {
    int add = (t >= o) ? sh[t - o] : 0;
    __syncthreads();
    sh[t] += add;
    __syncthreads();
  }
  if (i < n) off[i] = bs[blk] + sh[t] - v;
  if (i == n - 1) off[n] = bs[blk] + sh[t];
}

// XCD-sliced scatter (slice = blockIdx&7): each output slice dirtied by one XCD.
__global__ __launch_bounds__(256)
void scatter_kernel(const int* __restrict__ rows, const int* __restrict__ cols,
                    const uint8_t* __restrict__ mask,
                    const int* __restrict__ offU, const int* __restrict__ offI,
                    int* __restrict__ fillU, int* __restrict__ fillI,
                    int2* __restrict__ cpU, int2* __restrict__ cpI) {
  int slice = blockIdx.x & 7;
  int chunk = blockIdx.x >> 3;
  int base = chunk * EPC;
  int end = base + EPC; if (end > NE) end = NE;
  for (int e = base + threadIdx.x; e < end; e += 256) {
    int r = rows[e], c = cols[e];
    uint32_t m = mask[e];
    if (r / USLICE == slice) {
      int packed = c | (int)((m & 0xFu) << 17);
      int pu = offU[r] + atomicAdd(&fillU[r], 1);
      cpU[pu] = make_int2(packed, e);
    }
    if (c / ISLICE == slice) {
      int packed = r | (int)(((m >> 4) & 0xFu) << 17);
      int pi = offI[c] + atomicAdd(&fillI[c], 1);
      cpI[pi] = make_int2(packed, e);
    }
  }
}

// merged U+I gather-reduce SpMM, sub-wave layout: wave = 4 rows x 16 lanes,
// lane covers 4 dims via one dword fp8 load (cvt_f32_fp8 byte-select).
// layer0 (base!=null): d8 = fp8(raw*4/3), sum = bf16(base + raw/96)
// layer1: sum += raw/96 (bf16 RMW); optional fp8(sum*128) table out (s8*).
__global__ __launch_bounds__(256)
void spmm_layer_kernel(const int* __restrict__ offU, const int2* __restrict__ cpU,
                       const int* __restrict__ offI, const int2* __restrict__ cpI,
                       const float* __restrict__ esrc, int shift,
                       const uint8_t* __restrict__ SU, const uint8_t* __restrict__ SI,
                       uint8_t* __restrict__ dU, uint8_t* __restrict__ dI,
                       uint16_t* __restrict__ sumU, uint16_t* __restrict__ sumI,
                       const float* __restrict__ baseU, const float* __restrict__ baseI,
                       uint8_t* __restrict__ s8U, uint8_t* __restrict__ s8I) {
  int lane = threadIdx.x & 63;
  int g = lane >> 4, l15 = lane & 15;
  int w = (blockIdx.x * blockDim.x + threadIdx.x) >> 6;
  int r = w * 4 + g;                       // NU%4==0 -> wave never straddles U/I
  const int* off; const int2* cp; const uint8_t* S;
  uint8_t* D; uint16_t* Sum; const float* base; uint8_t* S8; int row;
  if (r < NU) {
    row = r; off = offU; cp = cpU; S = SU; D = dU; Sum = sumU; base = baseU; S8 = s8U;
  } else {
    row = r - NU; off = offI; cp = cpI; S = SI; D = dI; Sum = sumI; base = baseI; S8 = s8I;
  }
  int p0 = off[row], p1 = off[row + 1];
  f32x4 acc = {0.f, 0.f, 0.f, 0.f};
  int p = p0;
  for (; p + 2 <= p1; p += 2) {            // 2 gathers in flight per group
    int2 c0 = cp[p], c1 = cp[p + 1];
    uint32_t w0 = *(const uint32_t*)(S + ((size_t)(uint32_t)(c0.x & 0x1FFFF) << 6) + l15 * 4);
    uint32_t w1 = *(const uint32_t*)(S + ((size_t)(uint32_t)(c1.x & 0x1FFFF) << 6) + l15 * 4);
    float v0 = esrc[c0.y] * (float)((c0.x >> shift) & 1);
    float v1 = esrc[c1.y] * (float)((c1.x >> shift) & 1);
    acc[0] += v0 * fp8_sel<0>(w0) + v1 * fp8_sel<0>(w1);
    acc[1] += v0 * fp8_sel<1>(w0) + v1 * fp8_sel<1>(w1);
    acc[2] += v0 * fp8_sel<2>(w0) + v1 * fp8_sel<2>(w1);
    acc[3] += v0 * fp8_sel<3>(w0) + v1 * fp8_sel<3>(w1);
  }
  if (p < p1) {
    int2 c0 = cp[p];
    float v0 = esrc[c0.y] * (float)((c0.x >> shift) & 1);
    if (v0 != 0.f) {
      uint32_t w0 = *(const uint32_t*)(S + ((size_t)(uint32_t)(c0.x & 0x1FFFF) << 6) + l15 * 4);
      acc[0] += v0 * fp8_sel<0>(w0);
      acc[1] += v0 * fp8_sel<1>(w0);
      acc[2] += v0 * fp8_sel<2>(w0);
      acc[3] += v0 * fp8_sel<3>(w0);
    }
  }
  size_t idx = (size_t)row * DD + l15 * 4;
  if (D) {
    *(uint32_t*)(D + idx) = pack4_fp8(acc[0] * (4.0f / 3.0f), acc[1] * (4.0f / 3.0f),
                                      acc[2] * (4.0f / 3.0f), acc[3] * (4.0f / 3.0f));
    float4 b4 = *(const float4*)(base + idx);
    ushort4 s;
    s.x = f2bf(b4.x + acc[0] * SPMM_DESCALE);
    s.y = f2bf(b4.y + acc[1] * SPMM_DESCALE);
    s.z = f2bf(b4.z + acc[2] * SPMM_DESCALE);
    s.w = f2bf(b4.w + acc[3] * SPMM_DESCALE);
    *(ushort4*)(Sum + idx) = s;
  } else {
    ushort4 s = *(const ushort4*)(Sum + idx);
    float s0 = bf2f(s.x) + acc[0] * SPMM_DESCALE;
    float s1 = bf2f(s.y) + acc[1] * SPMM_DESCALE;
    float s2 = bf2f(s.z) + acc[2] * SPMM_DESCALE;
    float s3 = bf2f(s.w) + acc[3] * SPMM_DESCALE;
    s.x = f2bf(s0); s.y = f2bf(s1); s.z = f2bf(s2); s.w = f2bf(s3);
    *(ushort4*)(Sum + idx) = s;
    if (S8)
      *(uint32_t*)(S8 + idx) = pack4_fp8(s0 * FP8_SCALE, s1 * FP8_SCALE,
                                         s2 * FP8_SCALE, s3 * FP8_SCALE);
  }
}

// 4 edges per wave (16 lanes x 4 dims), fp8 sum tables (64B rows)
__global__ void edge_logit_kernel(const uint8_t* __restrict__ E8u,
                                  const uint8_t* __restrict__ E8i,
                                  const int* __restrict__ rows, const int* __restrict__ cols,
                                  const float* __restrict__ av, float* __restrict__ aug) {
  int lane = threadIdx.x & 63;
  int sub = lane >> 4, l15 = lane & 15;
  int w = (blockIdx.x * blockDim.x + threadIdx.x) >> 6;
  int nw = (gridDim.x * blockDim.x) >> 6;
  for (int b = w * 4; b < NE; b += nw * 4) {
    int e = b + sub;
    uint32_t wa = *(const uint32_t*)(E8u + ((size_t)rows[e] << 6) + l15 * 4);
    uint32_t wc = *(const uint32_t*)(E8i + ((size_t)cols[e] << 6) + l15 * 4);
    float p = fp8_sel<0>(wa) * fp8_sel<0>(wc) + fp8_sel<1>(wa) * fp8_sel<1>(wc) +
              fp8_sel<2>(wa) * fp8_sel<2>(wc) + fp8_sel<3>(wa) * fp8_sel<3>(wc);
#pragma unroll
    for (int off = 8; off > 0; off >>= 1) p += __shfl_down(p, off, 16);
    if (l15 == 0) aug[e] = av[e] / (1.0f + __expf(-p * EL_DESCALE));
  }
}

// both base tables fp32 -> fp8(x128) in one launch, 4 elems/thread
__global__ void cvt2_fp8_kernel(const float4* __restrict__ a, int na4, uint32_t* __restrict__ oa,
                                const float4* __restrict__ b, int nb4, uint32_t* __restrict__ ob) {
  int total = na4 + nb4;
  for (int i = blockIdx.x * blockDim.x + threadIdx.x; i < total; i += gridDim.x * blockDim.x) {
    float4 v = (i < na4) ? a[i] : b[i - na4];
    uint32_t w = pack4_fp8(v.x * FP8_SCALE, v.y * FP8_SCALE, v.z * FP8_SCALE, v.w * FP8_SCALE);
    if (i < na4) oa[i] = w; else ob[i - na4] = w;
  }
}

// gather both Z row sets; PRE-SCALE by LOG2E5 so PCL's MFMA emits
// already-log2-scaled logits (removes one fma per C element in the hot loop)
__global__ void gather2_rows_kernel(const uint16_t* __restrict__ Z16u, const int* __restrict__ uids,
                                    uint16_t* __restrict__ ou,
                                    const uint16_t* __restrict__ Z16i, const int* __restrict__ iids,
                                    uint16_t* __restrict__ oi) {
  int b = blockIdx.x, lane = threadIdx.x;
  if (b < BATCH)
    ou[(size_t)b * 64 + lane] = f2bf(bf2f(Z16u[(size_t)uids[b] * 64 + lane]) * LOG2E5);
  else {
    int bb = b - BATCH;
    oi[(size_t)bb * 64 + lane] = f2bf(bf2f(Z16i[(size_t)iids[bb] * 64 + lane]) * LOG2E5);
  }
}

// PCL denominator: S[m] += sum_n exp2(dot(Zg_scaled[m],E[n])), bf16 MFMA.
// Wave pins A-frags for EIGHT m-tiles (128 m-rows); A pre-scaled by LOG2E5.
// Grid/SPL per round-10 (dur 94/47 us): residency is register-capped (~2
// blocks/CU), so MORE iterations/block (not more blocks) is what amortizes
// the A-frag prologue -- round-11's 2x grid regressed 94->150 us.
__global__ __launch_bounds__(256)
void pcl_mfma4_kernel(const uint16_t* __restrict__ Zg, const uint16_t* __restrict__ E16,
                      int NT, int SPL, float* __restrict__ S) {
  int lane = threadIdx.x & 63;
  int wave = threadIdx.x >> 6;
  int quad = lane >> 4, l15 = lane & 15;
  int mt0 = (blockIdx.y * 4 + wave) * 8;       // 8 consecutive m-tiles per wave
  bf16x8 a0[8], a1[8];
#pragma unroll
  for (int i = 0; i < 8; ++i) {
    const uint16_t* ar = Zg + (size_t)((mt0 + i) * 16 + l15) * 64 + quad * 8;
    a0[i] = *(const bf16x8*)ar;
    a1[i] = *(const bf16x8*)(ar + 32);
  }
  f32x4 rs[8] = {};
  int nt = blockIdx.x;
  bf16x8 b0 = {}, b1 = {};
  if (nt < NT) {
    const uint16_t* br = E16 + (size_t)(nt * 16 + l15) * 64 + quad * 8;
    b0 = *(const bf16x8*)br;
    b1 = *(const bf16x8*)(br + 32);
  }
  while (nt < NT) {
    int nn = nt + SPL;
    bf16x8 p0 = {}, p1 = {};
    if (nn < NT) {
      const uint16_t* pr = E16 + (size_t)(nn * 16 + l15) * 64 + quad * 8;
      p0 = *(const bf16x8*)pr;
      p1 = *(const bf16x8*)(pr + 32);
    }
#pragma unroll
    for (int i = 0; i < 8; ++i) {
      f32x4 c = {0.f, 0.f, 0.f, 0.f};
      c = __builtin_amdgcn_mfma_f32_16x16x32_bf16(a0[i], b0, c, 0, 0, 0);
      c = __builtin_amdgcn_mfma_f32_16x16x32_bf16(a1[i], b1, c, 0, 0, 0);
#pragma unroll
      for (int r = 0; r < 4; ++r) rs[i][r] += __builtin_amdgcn_exp2f(c[r]);
    }
    b0 = p0; b1 = p1; nt = nn;
  }
#pragma unroll
  for (int off = 8; off > 0; off >>= 1) {
#pragma unroll
    for (int i = 0; i < 8; ++i)
#pragma unroll
      for (int r = 0; r < 4; ++r) rs[i][r] += __shfl_down(rs[i][r], off, 16);
  }
  if (l15 == 0) {
#pragma unroll
    for (int i = 0; i < 8; ++i)
#pragma unroll
      for (int r = 0; r < 4; ++r)
        atomicAdd(&S[(mt0 + i) * 16 + quad * 4 + r], rs[i][r]);
  }
}

__global__ void bpr_kernel(const uint16_t* __restrict__ E16u, const uint16_t* __restrict__ E16i,
                           const int* __restrict__ uids, const int* __restrict__ pos,
                           const int* __restrict__ neg, float* __restrict__ ps,
                           float* __restrict__ acc) {
  int lane = threadIdx.x & 63;
  int b = (blockIdx.x * blockDim.x + threadIdx.x) >> 6;
  if (b >= BATCH) return;
  float u = bf2f(E16u[(size_t)uids[b] * DD + lane]);
  float p = u * bf2f(E16i[(size_t)pos[b] * DD + lane]);
  float n = u * bf2f(E16i[(size_t)neg[b] * DD + lane]);
#pragma unroll
  for (int off = 32; off > 0; off >>= 1) { p += __shfl_down(p, off); n += __shfl_down(n, off); }
  if (lane == 0) {
    ps[b] = p;
    float x = p - n;
    atomicAdd(&acc[0], logf(1.0f / (1.0f + __expf(-x))));
  }
}

__global__ void minmax_kernel(const float* __restrict__ ps, float* __restrict__ mm) {
  __shared__ float smn[256], smx[256];
  int tid = threadIdx.x;
  float mn = 3.0e38f, mx = -3.0e38f;
  for (int i = tid; i < BATCH; i += 256) { float v = ps[i]; mn = fminf(mn, v); mx = fmaxf(mx, v); }
  smn[tid] = mn; smx[tid] = mx;
  __syncthreads();
  for (int s = 128; s > 0; s >>= 1) {
    if (tid < s) { smn[tid] = fminf(smn[tid], smn[tid + s]); smx[tid] = fmaxf(smx[tid], smx[tid + s]); }
    __syncthreads();
  }
  if (tid == 0) { mm[0] = smn[0]; mm[1] = smx[0]; }
}

__global__ void bcl_kernel(const uint16_t* __restrict__ E16u, const uint16_t* __restrict__ E16i,
                           const float* __restrict__ Eb, const int* __restrict__ uids,
                           const int* __restrict__ pos, const float* __restrict__ ps,
                           const float* __restrict__ mm, float* __restrict__ acc) {
  int lane = threadIdx.x & 63;
  int b = (blockIdx.x * blockDim.x + threadIdx.x) >> 6;
  if (b >= BATCH) return;
  float wgt = (ps[b] - mm[0]) / (mm[1] - mm[0] + 1e-9f);
  int rel = (int)(wgt * 10.0f);
  rel = rel < 0 ? 0 : (rel > 9 ? 9 : rel);
  float x = bf2f(E16u[(size_t)uids[b] * DD + lane]) * bf2f(E16i[(size_t)pos[b] * DD + lane]);
  float el = 1.0f / (1.0f + __expf(-x));
  float sneg = 0.f, spos = 0.f;
  for (int k = 0; k < NBK; ++k) {
    float d = el * Eb[k * DD + lane];
#pragma unroll
    for (int off = 32; off > 0; off >>= 1) d += __shfl_down(d, off);
    if (lane == 0) { if (k == rel) spos = d; else sneg += d; }
  }
  if (lane == 0) {
    atomicAdd(&acc[5], sneg * 0.1f);
    atomicAdd(&acc[6], spos);
  }
}

__global__ void pclpos2_kernel(const uint16_t* __restrict__ Z16u, const uint16_t* __restrict__ E16u,
                               const int* __restrict__ uids,
                               const uint16_t* __restrict__ Z16i, const uint16_t* __restrict__ E16i,
                               const int* __restrict__ iids, float* __restrict__ acc) {
  int lane = threadIdx.x & 63;
  int b = (blockIdx.x * blockDim.x + threadIdx.x) >> 6;
  if (b >= 2 * BATCH) return;
  const uint16_t *Z, *E; const int* ids; int idx, bb;
  if (b < BATCH) { Z = Z16u; E = E16u; ids = uids; idx = 3; bb = b; }
  else { Z = Z16i; E = E16i; ids = iids; idx = 4; bb = b - BATCH; }
  size_t r = (size_t)ids[bb] * DD + lane;
  float p = bf2f(Z[r]) * bf2f(E[r]);
#pragma unroll
  for (int off = 32; off > 0; off >>= 1) p += __shfl_down(p, off);
  if (lane == 0) {
    float x = p * 5.0f;
    x = fminf(5.0f, fmaxf(-5.0f, x));
    atomicAdd(&acc[idx], x);
  }
}

__global__ void sumsq3_kernel(const float* __restrict__ a, int na,
                              const float* __restrict__ b, int nb,
                              const float* __restrict__ c, int nc,
                              float* __restrict__ acc) {
  __shared__ float red[256];
  int tid = threadIdx.x;
  int total = na + nb + nc;
  float s = 0.f;
  for (int i = blockIdx.x * blockDim.x + tid; i < total; i += gridDim.x * blockDim.x) {
    float v = (i < na) ? a[i] : (i < na + nb) ? b[i - na] : c[i - na - nb];
    s += v * v;
  }
  red[tid] = s;
  __syncthreads();
  for (int st = 128; st > 0; st >>= 1) {
    if (tid < st) red[tid] += red[tid + st];
    __syncthreads();
  }
  if (tid == 0) atomicAdd(&acc[7], red[0]);
}

__global__ void finalize_kernel(const float* __restrict__ Su, const float* __restrict__ Si,
                                const float* __restrict__ acc, float* __restrict__ out) {
  __shared__ float r1[256], r2[256];
  int tid = threadIdx.x;
  float su = 0.f, si = 0.f;
  for (int b = tid; b < BATCH; b += 256) {
    su += logf(Su[b] + 1e-8f);
    si += logf(Si[b] + 1e-8f);
  }
  r1[tid] = su; r2[tid] = si;
  __syncthreads();
  for (int s = 128; s > 0; s >>= 1) {
    if (tid < s) { r1[tid] += r1[tid + s]; r2[tid] += r2[tid + s]; }
    __syncthreads();
  }
  if (tid == 0) {
    const float inv = 1.0f / (float)BATCH;
    float neg_s = (r1[0] + r2[0]) * inv;
    float pos_s = (acc[3] + acc[4]) * inv;
    float pcl = neg_s - pos_s;
    float bpr = -acc[0] * inv;
    float bcl = (acc[5] - acc[6]) * inv;
    float reg = 1e-7f * acc[7];
    float loss = bpr + 0.2f * pcl + 0.2f * bcl + reg;
    out[0] = loss; out[1] = bpr; out[2] = 0.2f * pcl; out[3] = 0.2f * bcl;
  }
}

extern "C" void kernel_launch(void* const* d_in, const int* in_sizes, int n_in,
                              void* d_out, int out_size, void* d_ws, size_t ws_size,
                              hipStream_t stream) {
  (void)in_sizes; (void)n_in; (void)out_size; (void)ws_size;
  const float* Eu0 = (const float*)d_in[0];
  const float* Ev0 = (const float*)d_in[1];
  const float* Eb  = (const float*)d_in[2];
  const float* av  = (const float*)d_in[3];
  const int* rows  = (const int*)d_in[4];
  const int* cols  = (const int*)d_in[5];
  const int* uids  = (const int*)d_in[6];
  const int* iids  = (const int*)d_in[7];
  const int* pos   = (const int*)d_in[8];
  const int* neg   = (const int*)d_in[9];
  float* out = (float*)d_out;

  float* w = (float*)d_ws;
  size_t o = 0;
  float* augv = w + o; o += NE;
  float* ps  = w + o; o += BATCH;
  float* Su  = w + o; o += BATCH;
  float* Si  = w + o; o += BATCH;
  float* acc = w + o; o += 16;
  float* mm  = w + o; o += 2;
  // bf16 running-sum tables + gathered Z rows
  uint16_t* hp = (uint16_t*)(w + o);
  uint16_t* E16u = hp; hp += (size_t)NU * DD;
  uint16_t* E16i = hp; hp += (size_t)NI * DD;
  uint16_t* Z16u = hp; hp += (size_t)NU * DD;
  uint16_t* Z16i = hp; hp += (size_t)NI * DD;
  uint16_t* Zgu  = hp; hp += (size_t)BATCH * DD;
  uint16_t* Zgi  = hp; hp += (size_t)BATCH * DD;
  // fp8 tables
  uint8_t* bp = (uint8_t*)hp;
  uint8_t* E0u8 = bp; bp += (size_t)NU * DD;    // fp8(128*Eu0)
  uint8_t* E0v8 = bp; bp += (size_t)NI * DD;
  uint8_t* d8U  = bp; bp += (size_t)NU * DD;    // layer0 outs (fp8, 128x)
  uint8_t* d8I  = bp; bp += (size_t)NI * DD;
  uint8_t* E8su = bp; bp += (size_t)NU * DD;    // fp8(128*E_u sums) for edge_logit
  uint8_t* E8si = bp; bp += (size_t)NI * DD;
  uint8_t* mask8 = bp; bp += NE;
  // int region (8B aligned)
  int* ip = (int*)(((uintptr_t)bp + 7) & ~(uintptr_t)7);
  int* offU = ip; ip += NU + 1;
  int* offI = ip; ip += NI + 1;
  int* cntU = ip; ip += NU;
  int* cntI = ip; ip += NI;
  ip += 2;
  int2* cpU = (int2*)ip; ip += 2 * (size_t)NE;
  int2* cpI = (int2*)ip; ip += 2 * (size_t)NE;

  // key chain: key(42) = (0,42); fold_in(k,d) = threefry2x32(k, [0,d])
  uint32_t bk[2][2];
  tf2x32(0u, 42u, 0u, 0u, bk[0][0], bk[0][1]);
  tf2x32(0u, 42u, 0u, 1u, bk[1][0], bk[1][1]);
  Keys8 K;
  for (int p = 0; p < 2; ++p)
    for (int l = 0; l < 2; ++l) {
      tf2x32(bk[p][0], bk[p][1], 0u, (uint32_t)(2 * l),     K.k[p * 2 + l][0], K.k[p * 2 + l][1]);
      tf2x32(bk[p][0], bk[p][1], 0u, (uint32_t)(2 * l + 1), K.k[4 + p * 2 + l][0], K.k[4 + p * 2 + l][1]);
    }

  const int nbU = (NU + SCAN_B - 1) / SCAN_B;
  const int nbI = (NI + SCAN_B - 1) / SCAN_B;

  cvt2_fp8_kernel<<<2048, 256, 0, stream>>>((const float4*)Eu0, NU * DD / 4, (uint32_t*)E0u8,
                                            (const float4*)Ev0, NI * DD / 4, (uint32_t*)E0v8);
  (void)hipMemsetAsync(cntU, 0, (size_t)(NU + NI) * sizeof(int), stream);
  mask_hist_kernel<<<(NE / 2 + 255) / 256, 256, 0, stream>>>(rows, cols, mask8, cntU, cntI, K);
  {
    int* bs = (int*)cpU;
    scan_phase1<<<nbU + nbI, SCAN_B, 0, stream>>>(cntU, cntI, nbU, bs);
    scan_phase2<<<1, 512, 0, stream>>>(bs, nbU, nbI);
    scan_phase3<<<nbU + nbI, SCAN_B, 0, stream>>>(cntU, cntI, nbU, bs, offU, offI);
  }
  (void)hipMemsetAsync(cntU, 0, (size_t)(NU + NI) * sizeof(int), stream);
  scatter_kernel<<<NCHUNK * NSLICE, 256, 0, stream>>>(rows, cols, mask8, offU, offI,
                                                      cntU, cntI, cpU, cpI);

  const int SPB = (NU + NI) / 16;   // 4 rows/wave, 4 waves/block -> 9375 blocks

  // ---- propagation 0 (mask bits 17/18) -> E16u/E16i (+fp8 sums) ----
  spmm_layer_kernel<<<SPB, 256, 0, stream>>>(offU, cpU, offI, cpI, av, 17,
                                             E0v8, E0u8, d8U, d8I,
                                             E16u, E16i, Eu0, Ev0, nullptr, nullptr);
  spmm_layer_kernel<<<SPB, 256, 0, stream>>>(offU, cpU, offI, cpI, av, 18,
                                             d8I, d8U, nullptr, nullptr,
                                             E16u, E16i, nullptr, nullptr, E8su, E8si);

  edge_logit_kernel<<<4096, 256, 0, stream>>>(E8su, E8si, rows, cols, av, augv);

  // ---- propagation 1 (mask bits 19/20) -> Z16u/Z16i ----
  spmm_layer_kernel<<<SPB, 256, 0, stream>>>(offU, cpU, offI, cpI, augv, 19,
                                             E0v8, E0u8, d8U, d8I,
                                             Z16u, Z16i, Eu0, Ev0, nullptr, nullptr);
  spmm_layer_kernel<<<SPB, 256, 0, stream>>>(offU, cpU, offI, cpI, augv, 20,
                                             d8I, d8U, nullptr, nullptr,
                                             Z16u, Z16i, nullptr, nullptr, nullptr, nullptr);

  gather2_rows_kernel<<<2 * BATCH, 64, 0, stream>>>(Z16u, uids, Zgu, Z16i, iids, Zgi);

  (void)hipMemsetAsync(Su, 0, (2 * BATCH + 16) * sizeof(float), stream);

  bpr_kernel<<<BATCH / 4, 256, 0, stream>>>(E16u, E16i, uids, pos, neg, ps, acc);
  minmax_kernel<<<1, 256, 0, stream>>>(ps, mm);
  bcl_kernel<<<BATCH / 4, 256, 0, stream>>>(E16u, E16i, Eb, uids, pos, ps, mm, acc);

  // PCL denominators: round-10 proven grids (24 iters/block)
  pcl_mfma4_kernel<<<dim3(256, 4), 256, 0, stream>>>(Zgu, E16u, NU / 16, 256, Su);
  pcl_mfma4_kernel<<<dim3(128, 4), 256, 0, stream>>>(Zgi, E16i, NI / 16, 128, Si);

  pclpos2_kernel<<<2 * BATCH / 4, 256, 0, stream>>>(Z16u, E16u, uids, Z16i, E16i, iids, acc);

  sumsq3_kernel<<<1024, 256, 0, stream>>>(Eu0, NU * DD, Ev0, NI * DD, Eb, NBK * DD, acc);

  finalize_kernel<<<1, 256, 0, stream>>>(Su, Si, acc, out);
}

// Round 13
// 886.190 us; speedup vs baseline: 1.1038x; 1.0132x over previous
//
#include <hip/hip_runtime.h>
#include <stdint.h>

#define NU 100000
#define NI 50000
#define NBK 10
#define DD 64
#define NE 1000000
#define BATCH 2048
#define NSLICE 8
#define USLICE ((NU + NSLICE - 1) / NSLICE)   // 12500
#define ISLICE ((NI + NSLICE - 1) / NSLICE)   // 6250
#define NCHUNK 512
#define EPC ((NE + NCHUNK - 1) / NCHUNK)      // 1954
// fp8 storage scale: embeddings ~0.01 are subnormal in e4m3; x128 -> normal.
// Combined descale: (4/3 dropout) / 128 = 1/96.
#define FP8_SCALE 128.0f
#define SPMM_DESCALE (1.0f / 96.0f)
#define EL_DESCALE (1.0f / 16384.0f)   // edge-logit dot of two 128x fp8 tables
#define LOG2E5 7.2134752f              // 5*log2(e): exp(5x) = 2^(x*LOG2E5)

typedef __bf16 bf16x8 __attribute__((ext_vector_type(8)));
typedef float f32x4 __attribute__((ext_vector_type(4)));

struct Keys8 { uint32_t k[8][2]; };

// ---------------- threefry2x32 (JAX-compatible, 20 rounds) ----------------
__host__ __device__ inline void tf2x32(uint32_t k0, uint32_t k1, uint32_t x0, uint32_t x1,
                                       uint32_t& o0, uint32_t& o1) {
  uint32_t ks0 = k0, ks1 = k1, ks2 = k0 ^ k1 ^ 0x1BD11BDAu;
  x0 += ks0; x1 += ks1;
#define TFR(r) { x0 += x1; x1 = (x1 << (r)) | (x1 >> (32 - (r))); x1 ^= x0; }
  TFR(13) TFR(15) TFR(26) TFR(6)   x0 += ks1; x1 += ks2 + 1u;
  TFR(17) TFR(29) TFR(16) TFR(24)  x0 += ks2; x1 += ks0 + 2u;
  TFR(13) TFR(15) TFR(26) TFR(6)   x0 += ks0; x1 += ks1 + 3u;
  TFR(17) TFR(29) TFR(16) TFR(24)  x0 += ks1; x1 += ks2 + 4u;
  TFR(13) TFR(15) TFR(26) TFR(6)   x0 += ks2; x1 += ks0 + 5u;
#undef TFR
  o0 = x0; o1 = x1;
}

__device__ inline uint16_t f2bf(float f) {
  uint32_t u = __float_as_uint(f);
  return (uint16_t)((u + 0x7fffu + ((u >> 16) & 1u)) >> 16);   // RNE
}
__device__ inline float bf2f(uint16_t u) {
  return __uint_as_float(((uint32_t)u) << 16);
}

// ---- fp8 e4m3 (OCP) helpers ----
// byte-select must be an immediate for the builtin -> template parameter
template <int SEL>
__device__ inline float fp8_sel(uint32_t w) {
#if __has_builtin(__builtin_amdgcn_cvt_f32_fp8)
  return __builtin_amdgcn_cvt_f32_fp8((int)w, SEL);
#else
  uint32_t b = (w >> (8 * SEL)) & 0xFFu;
  uint32_t s = b >> 7, e = (b >> 3) & 0xF, m = b & 7;
  float v = (e == 0) ? (float)m * (1.0f / 512.0f)
                     : __uint_as_float(((e + 120) << 23) | (m << 20));
  return s ? -v : v;
#endif
}
__device__ inline uint32_t f32_to_fp8(float f) {
#if __has_builtin(__builtin_amdgcn_cvt_pk_fp8_f32)
  return (uint32_t)__builtin_amdgcn_cvt_pk_fp8_f32(f, f, 0, false) & 0xFFu;
#else
  uint32_t s = (__float_as_uint(f) >> 31) << 7;
  float a = fabsf(f);
  a = fminf(a, 448.0f);
  if (a < 0.015625f) {
    uint32_t m = (uint32_t)(a * 512.0f + 0.5f);
    return s | m;
  }
  int ex; float fr = frexpf(a, &ex);
  uint32_t q = (uint32_t)(fr * 16.0f + 0.5f);
  int E = ex + 6;
  if (q == 16) { q = 8; E += 1; }
  if (E > 15) { E = 15; q = 14; }
  if (E == 15 && q == 15) q = 14;
  return s | ((uint32_t)E << 3) | (q - 8);
#endif
}
__device__ inline uint32_t pack4_fp8(float a, float b, float c, float d) {
  return f32_to_fp8(a) | (f32_to_fp8(b) << 8) | (f32_to_fp8(c) << 16) | (f32_to_fp8(d) << 24);
}

// dropout masks for edge pair (e, e+half) from ONE threefry eval per key:
// o0 -> element e, o1 -> element e+half (JAX split-iota semantics).
__global__ void mask_hist_kernel(const int* __restrict__ rows, const int* __restrict__ cols,
                                 uint8_t* __restrict__ mask,
                                 int* __restrict__ cntU, int* __restrict__ cntI, Keys8 K) {
  const int half = NE / 2;
  int e = blockIdx.x * blockDim.x + threadIdx.x;
  if (e >= half) return;
  uint32_t mlo = 0, mhi = 0;
#pragma unroll
  for (int j = 0; j < 8; ++j) {
    uint32_t o0, o1;
    tf2x32(K.k[j][0], K.k[j][1], (uint32_t)e, (uint32_t)(e + half), o0, o1);
    float u0 = __uint_as_float((o0 >> 9) | 0x3f800000u) - 1.0f;
    float u1 = __uint_as_float((o1 >> 9) | 0x3f800000u) - 1.0f;
    mlo |= (u0 < 0.75f ? 1u : 0u) << j;
    mhi |= (u1 < 0.75f ? 1u : 0u) << j;
  }
  mask[e] = (uint8_t)mlo;
  mask[e + half] = (uint8_t)mhi;
  atomicAdd(&cntU[rows[e]], 1);
  atomicAdd(&cntI[cols[e]], 1);
  atomicAdd(&cntU[rows[e + half]], 1);
  atomicAdd(&cntI[cols[e + half]], 1);
}

#define SCAN_B 256
__global__ void scan_phase1(const int* __restrict__ cntU, const int* __restrict__ cntI,
                            int nbU, int* __restrict__ bs) {
  __shared__ int red[SCAN_B];
  int blk = blockIdx.x, t = threadIdx.x;
  const int* cnt; int n, j;
  if (blk < nbU) { cnt = cntU; n = NU; j = blk; }
  else { cnt = cntI; n = NI; j = blk - nbU; }
  int i = j * SCAN_B + t;
  red[t] = (i < n) ? cnt[i] : 0;
  __syncthreads();
  for (int s = 128; s > 0; s >>= 1) {
    if (t < s) red[t] += red[t + s];
    __syncthreads();
  }
  if (t == 0) bs[blk] = red[0];
}
__global__ void scan_phase2(int* __restrict__ bs, int nbU, int nbI) {
  __shared__ int sh[512];
  int t = threadIdx.x;
  int v = (t < nbU) ? bs[t] : 0;
  sh[t] = v;
  __syncthreads();
  for (int off = 1; off < 512; off <<= 1) {
    int add = (t >= off) ? sh[t - off] : 0;
    __syncthreads();
    sh[t] += add;
    __syncthreads();
  }
  if (t < nbU) bs[t] = sh[t] - v;
  __syncthreads();
  int v2 = (t < nbI) ? bs[nbU + t] : 0;
  sh[t] = v2;
  __syncthreads();
  for (int off = 1; off < 512; off <<= 1) {
    int add = (t >= off) ? sh[t - off] : 0;
    __syncthreads();
    sh[t] += add;
    __syncthreads();
  }
  if (t < nbI) bs[nbU + t] = sh[t] - v2;
}
__global__ void scan_phase3(const int* __restrict__ cntU, const int* __restrict__ cntI,
                            int nbU, const int* __restrict__ bs,
                            int* __restrict__ offU, int* __restrict__ offI) {
  __shared__ int sh[SCAN_B];
  int blk = blockIdx.x, t = threadIdx.x;
  const int* cnt; int n, j; int* off;
  if (blk < nbU) { cnt = cntU; n = NU; j = blk; off = offU; }
  else { cnt = cntI; n = NI; j = blk - nbU; off = offI; }
  int i = j * SCAN_B + t;
  int v = (i < n) ? cnt[i] : 0;
  sh[t] = v;
  __syncthreads();
  for (int o = 1; o < SCAN_B; o <<= 1) {
    int add = (t >= o) ? sh[t - o] : 0;
    __syncthreads();
    sh[t] += add;
    __syncthreads();
  }
  if (i < n) off[i] = bs[blk] + sh[t] - v;
  if (i == n - 1) off[n] = bs[blk] + sh[t];
}

// XCD-sliced scatter (slice = blockIdx&7): each output slice dirtied by one XCD.
__global__ __launch_bounds__(256)
void scatter_kernel(const int* __restrict__ rows, const int* __restrict__ cols,
                    const uint8_t* __restrict__ mask,
                    const int* __restrict__ offU, const int* __restrict__ offI,
                    int* __restrict__ fillU, int* __restrict__ fillI,
                    int2* __restrict__ cpU, int2* __restrict__ cpI) {
  int slice = blockIdx.x & 7;
  int chunk = blockIdx.x >> 3;
  int base = chunk * EPC;
  int end = base + EPC; if (end > NE) end = NE;
  for (int e = base + threadIdx.x; e < end; e += 256) {
    int r = rows[e], c = cols[e];
    uint32_t m = mask[e];
    if (r / USLICE == slice) {
      int packed = c | (int)((m & 0xFu) << 17);
      int pu = offU[r] + atomicAdd(&fillU[r], 1);
      cpU[pu] = make_int2(packed, e);
    }
    if (c / ISLICE == slice) {
      int packed = r | (int)(((m >> 4) & 0xFu) << 17);
      int pi = offI[c] + atomicAdd(&fillI[c], 1);
      cpI[pi] = make_int2(packed, e);
    }
  }
}

// merged U+I gather-reduce SpMM, sub-wave layout: wave = 4 rows x 16 lanes,
// lane covers 4 dims via one dword fp8 load (cvt_f32_fp8 byte-select).
__global__ __launch_bounds__(256)
void spmm_layer_kernel(const int* __restrict__ offU, const int2* __restrict__ cpU,
                       const int* __restrict__ offI, const int2* __restrict__ cpI,
                       const float* __restrict__ esrc, int shift,
                       const uint8_t* __restrict__ SU, const uint8_t* __restrict__ SI,
                       uint8_t* __restrict__ dU, uint8_t* __restrict__ dI,
                       uint16_t* __restrict__ sumU, uint16_t* __restrict__ sumI,
                       const float* __restrict__ baseU, const float* __restrict__ baseI,
                       uint8_t* __restrict__ s8U, uint8_t* __restrict__ s8I) {
  int lane = threadIdx.x & 63;
  int g = lane >> 4, l15 = lane & 15;
  int w = (blockIdx.x * blockDim.x + threadIdx.x) >> 6;
  int r = w * 4 + g;                       // NU%4==0 -> wave never straddles U/I
  const int* off; const int2* cp; const uint8_t* S;
  uint8_t* D; uint16_t* Sum; const float* base; uint8_t* S8; int row;
  if (r < NU) {
    row = r; off = offU; cp = cpU; S = SU; D = dU; Sum = sumU; base = baseU; S8 = s8U;
  } else {
    row = r - NU; off = offI; cp = cpI; S = SI; D = dI; Sum = sumI; base = baseI; S8 = s8I;
  }
  int p0 = off[row], p1 = off[row + 1];
  f32x4 acc = {0.f, 0.f, 0.f, 0.f};
  int p = p0;
  for (; p + 2 <= p1; p += 2) {            // 2 gathers in flight per group
    int2 c0 = cp[p], c1 = cp[p + 1];
    uint32_t w0 = *(const uint32_t*)(S + ((size_t)(uint32_t)(c0.x & 0x1FFFF) << 6) + l15 * 4);
    uint32_t w1 = *(const uint32_t*)(S + ((size_t)(uint32_t)(c1.x & 0x1FFFF) << 6) + l15 * 4);
    float v0 = esrc[c0.y] * (float)((c0.x >> shift) & 1);
    float v1 = esrc[c1.y] * (float)((c1.x >> shift) & 1);
    acc[0] += v0 * fp8_sel<0>(w0) + v1 * fp8_sel<0>(w1);
    acc[1] += v0 * fp8_sel<1>(w0) + v1 * fp8_sel<1>(w1);
    acc[2] += v0 * fp8_sel<2>(w0) + v1 * fp8_sel<2>(w1);
    acc[3] += v0 * fp8_sel<3>(w0) + v1 * fp8_sel<3>(w1);
  }
  if (p < p1) {
    int2 c0 = cp[p];
    float v0 = esrc[c0.y] * (float)((c0.x >> shift) & 1);
    if (v0 != 0.f) {
      uint32_t w0 = *(const uint32_t*)(S + ((size_t)(uint32_t)(c0.x & 0x1FFFF) << 6) + l15 * 4);
      acc[0] += v0 * fp8_sel<0>(w0);
      acc[1] += v0 * fp8_sel<1>(w0);
      acc[2] += v0 * fp8_sel<2>(w0);
      acc[3] += v0 * fp8_sel<3>(w0);
    }
  }
  size_t idx = (size_t)row * DD + l15 * 4;
  if (D) {
    *(uint32_t*)(D + idx) = pack4_fp8(acc[0] * (4.0f / 3.0f), acc[1] * (4.0f / 3.0f),
                                      acc[2] * (4.0f / 3.0f), acc[3] * (4.0f / 3.0f));
    float4 b4 = *(const float4*)(base + idx);
    ushort4 s;
    s.x = f2bf(b4.x + acc[0] * SPMM_DESCALE);
    s.y = f2bf(b4.y + acc[1] * SPMM_DESCALE);
    s.z = f2bf(b4.z + acc[2] * SPMM_DESCALE);
    s.w = f2bf(b4.w + acc[3] * SPMM_DESCALE);
    *(ushort4*)(Sum + idx) = s;
  } else {
    ushort4 s = *(const ushort4*)(Sum + idx);
    float s0 = bf2f(s.x) + acc[0] * SPMM_DESCALE;
    float s1 = bf2f(s.y) + acc[1] * SPMM_DESCALE;
    float s2 = bf2f(s.z) + acc[2] * SPMM_DESCALE;
    float s3 = bf2f(s.w) + acc[3] * SPMM_DESCALE;
    s.x = f2bf(s0); s.y = f2bf(s1); s.z = f2bf(s2); s.w = f2bf(s3);
    *(ushort4*)(Sum + idx) = s;
    if (S8)
      *(uint32_t*)(S8 + idx) = pack4_fp8(s0 * FP8_SCALE, s1 * FP8_SCALE,
                                         s2 * FP8_SCALE, s3 * FP8_SCALE);
  }
}

// 4 edges per wave (16 lanes x 4 dims), fp8 sum tables (64B rows)
__global__ void edge_logit_kernel(const uint8_t* __restrict__ E8u,
                                  const uint8_t* __restrict__ E8i,
                                  const int* __restrict__ rows, const int* __restrict__ cols,
                                  const float* __restrict__ av, float* __restrict__ aug) {
  int lane = threadIdx.x & 63;
  int sub = lane >> 4, l15 = lane & 15;
  int w = (blockIdx.x * blockDim.x + threadIdx.x) >> 6;
  int nw = (gridDim.x * blockDim.x) >> 6;
  for (int b = w * 4; b < NE; b += nw * 4) {
    int e = b + sub;
    uint32_t wa = *(const uint32_t*)(E8u + ((size_t)rows[e] << 6) + l15 * 4);
    uint32_t wc = *(const uint32_t*)(E8i + ((size_t)cols[e] << 6) + l15 * 4);
    float p = fp8_sel<0>(wa) * fp8_sel<0>(wc) + fp8_sel<1>(wa) * fp8_sel<1>(wc) +
              fp8_sel<2>(wa) * fp8_sel<2>(wc) + fp8_sel<3>(wa) * fp8_sel<3>(wc);
#pragma unroll
    for (int off = 8; off > 0; off >>= 1) p += __shfl_down(p, off, 16);
    if (l15 == 0) aug[e] = av[e] / (1.0f + __expf(-p * EL_DESCALE));
  }
}

// both base tables fp32 -> fp8(x128) in one launch, 4 elems/thread
__global__ void cvt2_fp8_kernel(const float4* __restrict__ a, int na4, uint32_t* __restrict__ oa,
                                const float4* __restrict__ b, int nb4, uint32_t* __restrict__ ob) {
  int total = na4 + nb4;
  for (int i = blockIdx.x * blockDim.x + threadIdx.x; i < total; i += gridDim.x * blockDim.x) {
    float4 v = (i < na4) ? a[i] : b[i - na4];
    uint32_t w = pack4_fp8(v.x * FP8_SCALE, v.y * FP8_SCALE, v.z * FP8_SCALE, v.w * FP8_SCALE);
    if (i < na4) oa[i] = w; else ob[i - na4] = w;
  }
}

// gather both Z row sets; PRE-SCALE by LOG2E5 so PCL's MFMA emits
// already-log2-scaled logits
__global__ void gather2_rows_kernel(const uint16_t* __restrict__ Z16u, const int* __restrict__ uids,
                                    uint16_t* __restrict__ ou,
                                    const uint16_t* __restrict__ Z16i, const int* __restrict__ iids,
                                    uint16_t* __restrict__ oi) {
  int b = blockIdx.x, lane = threadIdx.x;
  if (b < BATCH)
    ou[(size_t)b * 64 + lane] = f2bf(bf2f(Z16u[(size_t)uids[b] * 64 + lane]) * LOG2E5);
  else {
    int bb = b - BATCH;
    oi[(size_t)bb * 64 + lane] = f2bf(bf2f(Z16i[(size_t)iids[bb] * 64 + lane]) * LOG2E5);
  }
}

// PCL denominator: S[m] += sum_n exp2(dot(Zg_scaled[m],E[n])), bf16 MFMA.
// FOUR m-tiles/wave (~90 regs incl. AGPRs -> ~5 waves/SIMD resident, vs the
// 8-tile version's ~176 regs -> 2 waves/SIMD at 23% occupancy / 104 us).
// m covered by y=8 x 4 waves x 4 tiles = 128 tiles; grid x=SPL=128 ->
// 1024 blocks = 4 blocks/CU in ONE residency round, ~49 iters/block (U).
__global__ __launch_bounds__(256)
void pcl_mfma5_kernel(const uint16_t* __restrict__ Zg, const uint16_t* __restrict__ E16,
                      int NT, int SPL, float* __restrict__ S) {
  int lane = threadIdx.x & 63;
  int wave = threadIdx.x >> 6;
  int quad = lane >> 4, l15 = lane & 15;
  int mt0 = (blockIdx.y * 4 + wave) * 4;       // 4 consecutive m-tiles per wave
  bf16x8 a0[4], a1[4];
#pragma unroll
  for (int i = 0; i < 4; ++i) {
    const uint16_t* ar = Zg + (size_t)((mt0 + i) * 16 + l15) * 64 + quad * 8;
    a0[i] = *(const bf16x8*)ar;
    a1[i] = *(const bf16x8*)(ar + 32);
  }
  f32x4 rs[4] = {};
  int nt = blockIdx.x;
  bf16x8 b0 = {}, b1 = {};
  if (nt < NT) {
    const uint16_t* br = E16 + (size_t)(nt * 16 + l15) * 64 + quad * 8;
    b0 = *(const bf16x8*)br;
    b1 = *(const bf16x8*)(br + 32);
  }
  while (nt < NT) {
    int nn = nt + SPL;
    bf16x8 p0 = {}, p1 = {};
    if (nn < NT) {
      const uint16_t* pr = E16 + (size_t)(nn * 16 + l15) * 64 + quad * 8;
      p0 = *(const bf16x8*)pr;
      p1 = *(const bf16x8*)(pr + 32);
    }
#pragma unroll
    for (int i = 0; i < 4; ++i) {
      f32x4 c = {0.f, 0.f, 0.f, 0.f};
      c = __builtin_amdgcn_mfma_f32_16x16x32_bf16(a0[i], b0, c, 0, 0, 0);
      c = __builtin_amdgcn_mfma_f32_16x16x32_bf16(a1[i], b1, c, 0, 0, 0);
#pragma unroll
      for (int r = 0; r < 4; ++r) rs[i][r] += __builtin_amdgcn_exp2f(c[r]);
    }
    b0 = p0; b1 = p1; nt = nn;
  }
#pragma unroll
  for (int off = 8; off > 0; off >>= 1) {
#pragma unroll
    for (int i = 0; i < 4; ++i)
#pragma unroll
      for (int r = 0; r < 4; ++r) rs[i][r] += __shfl_down(rs[i][r], off, 16);
  }
  if (l15 == 0) {
#pragma unroll
    for (int i = 0; i < 4; ++i)
#pragma unroll
      for (int r = 0; r < 4; ++r)
        atomicAdd(&S[(mt0 + i) * 16 + quad * 4 + r], rs[i][r]);
  }
}

__global__ void bpr_kernel(const uint16_t* __restrict__ E16u, const uint16_t* __restrict__ E16i,
                           const int* __restrict__ uids, const int* __restrict__ pos,
                           const int* __restrict__ neg, float* __restrict__ ps,
                           float* __restrict__ acc) {
  int lane = threadIdx.x & 63;
  int b = (blockIdx.x * blockDim.x + threadIdx.x) >> 6;
  if (b >= BATCH) return;
  float u = bf2f(E16u[(size_t)uids[b] * DD + lane]);
  float p = u * bf2f(E16i[(size_t)pos[b] * DD + lane]);
  float n = u * bf2f(E16i[(size_t)neg[b] * DD + lane]);
#pragma unroll
  for (int off = 32; off > 0; off >>= 1) { p += __shfl_down(p, off); n += __shfl_down(n, off); }
  if (lane == 0) {
    ps[b] = p;
    float x = p - n;
    atomicAdd(&acc[0], logf(1.0f / (1.0f + __expf(-x))));
  }
}

__global__ void minmax_kernel(const float* __restrict__ ps, float* __restrict__ mm) {
  __shared__ float smn[256], smx[256];
  int tid = threadIdx.x;
  float mn = 3.0e38f, mx = -3.0e38f;
  for (int i = tid; i < BATCH; i += 256) { float v = ps[i]; mn = fminf(mn, v); mx = fmaxf(mx, v); }
  smn[tid] = mn; smx[tid] = mx;
  __syncthreads();
  for (int s = 128; s > 0; s >>= 1) {
    if (tid < s) { smn[tid] = fminf(smn[tid], smn[tid + s]); smx[tid] = fmaxf(smx[tid], smx[tid + s]); }
    __syncthreads();
  }
  if (tid == 0) { mm[0] = smn[0]; mm[1] = smx[0]; }
}

__global__ void bcl_kernel(const uint16_t* __restrict__ E16u, const uint16_t* __restrict__ E16i,
                           const float* __restrict__ Eb, const int* __restrict__ uids,
                           const int* __restrict__ pos, const float* __restrict__ ps,
                           const float* __restrict__ mm, float* __restrict__ acc) {
  int lane = threadIdx.x & 63;
  int b = (blockIdx.x * blockDim.x + threadIdx.x) >> 6;
  if (b >= BATCH) return;
  float wgt = (ps[b] - mm[0]) / (mm[1] - mm[0] + 1e-9f);
  int rel = (int)(wgt * 10.0f);
  rel = rel < 0 ? 0 : (rel > 9 ? 9 : rel);
  float x = bf2f(E16u[(size_t)uids[b] * DD + lane]) * bf2f(E16i[(size_t)pos[b] * DD + lane]);
  float el = 1.0f / (1.0f + __expf(-x));
  float sneg = 0.f, spos = 0.f;
  for (int k = 0; k < NBK; ++k) {
    float d = el * Eb[k * DD + lane];
#pragma unroll
    for (int off = 32; off > 0; off >>= 1) d += __shfl_down(d, off);
    if (lane == 0) { if (k == rel) spos = d; else sneg += d; }
  }
  if (lane == 0) {
    atomicAdd(&acc[5], sneg * 0.1f);
    atomicAdd(&acc[6], spos);
  }
}

__global__ void pclpos2_kernel(const uint16_t* __restrict__ Z16u, const uint16_t* __restrict__ E16u,
                               const int* __restrict__ uids,
                               const uint16_t* __restrict__ Z16i, const uint16_t* __restrict__ E16i,
                               const int* __restrict__ iids, float* __restrict__ acc) {
  int lane = threadIdx.x & 63;
  int b = (blockIdx.x * blockDim.x + threadIdx.x) >> 6;
  if (b >= 2 * BATCH) return;
  const uint16_t *Z, *E; const int* ids; int idx, bb;
  if (b < BATCH) { Z = Z16u; E = E16u; ids = uids; idx = 3; bb = b; }
  else { Z = Z16i; E = E16i; ids = iids; idx = 4; bb = b - BATCH; }
  size_t r = (size_t)ids[bb] * DD + lane;
  float p = bf2f(Z[r]) * bf2f(E[r]);
#pragma unroll
  for (int off = 32; off > 0; off >>= 1) p += __shfl_down(p, off);
  if (lane == 0) {
    float x = p * 5.0f;
    x = fminf(5.0f, fmaxf(-5.0f, x));
    atomicAdd(&acc[idx], x);
  }
}

__global__ void sumsq3_kernel(const float* __restrict__ a, int na,
                              const float* __restrict__ b, int nb,
                              const float* __restrict__ c, int nc,
                              float* __restrict__ acc) {
  __shared__ float red[256];
  int tid = threadIdx.x;
  int total = na + nb + nc;
  float s = 0.f;
  for (int i = blockIdx.x * blockDim.x + tid; i < total; i += gridDim.x * blockDim.x) {
    float v = (i < na) ? a[i] : (i < na + nb) ? b[i - na] : c[i - na - nb];
    s += v * v;
  }
  red[tid] = s;
  __syncthreads();
  for (int st = 128; st > 0; st >>= 1) {
    if (tid < st) red[tid] += red[tid + st];
    __syncthreads();
  }
  if (tid == 0) atomicAdd(&acc[7], red[0]);
}

__global__ void finalize_kernel(const float* __restrict__ Su, const float* __restrict__ Si,
                                const float* __restrict__ acc, float* __restrict__ out) {
  __shared__ float r1[256], r2[256];
  int tid = threadIdx.x;
  float su = 0.f, si = 0.f;
  for (int b = tid; b < BATCH; b += 256) {
    su += logf(Su[b] + 1e-8f);
    si += logf(Si[b] + 1e-8f);
  }
  r1[tid] = su; r2[tid] = si;
  __syncthreads();
  for (int s = 128; s > 0; s >>= 1) {
    if (tid < s) { r1[tid] += r1[tid + s]; r2[tid] += r2[tid + s]; }
    __syncthreads();
  }
  if (tid == 0) {
    const float inv = 1.0f / (float)BATCH;
    float neg_s = (r1[0] + r2[0]) * inv;
    float pos_s = (acc[3] + acc[4]) * inv;
    float pcl = neg_s - pos_s;
    float bpr = -acc[0] * inv;
    float bcl = (acc[5] - acc[6]) * inv;
    float reg = 1e-7f * acc[7];
    float loss = bpr + 0.2f * pcl + 0.2f * bcl + reg;
    out[0] = loss; out[1] = bpr; out[2] = 0.2f * pcl; out[3] = 0.2f * bcl;
  }
}

extern "C" void kernel_launch(void* const* d_in, const int* in_sizes, int n_in,
                              void* d_out, int out_size, void* d_ws, size_t ws_size,
                              hipStream_t stream) {
  (void)in_sizes; (void)n_in; (void)out_size; (void)ws_size;
  const float* Eu0 = (const float*)d_in[0];
  const float* Ev0 = (const float*)d_in[1];
  const float* Eb  = (const float*)d_in[2];
  const float* av  = (const float*)d_in[3];
  const int* rows  = (const int*)d_in[4];
  const int* cols  = (const int*)d_in[5];
  const int* uids  = (const int*)d_in[6];
  const int* iids  = (const int*)d_in[7];
  const int* pos   = (const int*)d_in[8];
  const int* neg   = (const int*)d_in[9];
  float* out = (float*)d_out;

  float* w = (float*)d_ws;
  size_t o = 0;
  float* augv = w + o; o += NE;
  float* ps  = w + o; o += BATCH;
  float* Su  = w + o; o += BATCH;
  float* Si  = w + o; o += BATCH;
  float* acc = w + o; o += 16;
  float* mm  = w + o; o += 2;
  // bf16 running-sum tables + gathered Z rows
  uint16_t* hp = (uint16_t*)(w + o);
  uint16_t* E16u = hp; hp += (size_t)NU * DD;
  uint16_t* E16i = hp; hp += (size_t)NI * DD;
  uint16_t* Z16u = hp; hp += (size_t)NU * DD;
  uint16_t* Z16i = hp; hp += (size_t)NI * DD;
  uint16_t* Zgu  = hp; hp += (size_t)BATCH * DD;
  uint16_t* Zgi  = hp; hp += (size_t)BATCH * DD;
  // fp8 tables
  uint8_t* bp = (uint8_t*)hp;
  uint8_t* E0u8 = bp; bp += (size_t)NU * DD;    // fp8(128*Eu0)
  uint8_t* E0v8 = bp; bp += (size_t)NI * DD;
  uint8_t* d8U  = bp; bp += (size_t)NU * DD;    // layer0 outs (fp8, 128x)
  uint8_t* d8I  = bp; bp += (size_t)NI * DD;
  uint8_t* E8su = bp; bp += (size_t)NU * DD;    // fp8(128*E_u sums) for edge_logit
  uint8_t* E8si = bp; bp += (size_t)NI * DD;
  uint8_t* mask8 = bp; bp += NE;
  // int region (8B aligned)
  int* ip = (int*)(((uintptr_t)bp + 7) & ~(uintptr_t)7);
  int* offU = ip; ip += NU + 1;
  int* offI = ip; ip += NI + 1;
  int* cntU = ip; ip += NU;
  int* cntI = ip; ip += NI;
  ip += 2;
  int2* cpU = (int2*)ip; ip += 2 * (size_t)NE;
  int2* cpI = (int2*)ip; ip += 2 * (size_t)NE;

  // key chain: key(42) = (0,42); fold_in(k,d) = threefry2x32(k, [0,d])
  uint32_t bk[2][2];
  tf2x32(0u, 42u, 0u, 0u, bk[0][0], bk[0][1]);
  tf2x32(0u, 42u, 0u, 1u, bk[1][0], bk[1][1]);
  Keys8 K;
  for (int p = 0; p < 2; ++p)
    for (int l = 0; l < 2; ++l) {
      tf2x32(bk[p][0], bk[p][1], 0u, (uint32_t)(2 * l),     K.k[p * 2 + l][0], K.k[p * 2 + l][1]);
      tf2x32(bk[p][0], bk[p][1], 0u, (uint32_t)(2 * l + 1), K.k[4 + p * 2 + l][0], K.k[4 + p * 2 + l][1]);
    }

  const int nbU = (NU + SCAN_B - 1) / SCAN_B;
  const int nbI = (NI + SCAN_B - 1) / SCAN_B;

  cvt2_fp8_kernel<<<2048, 256, 0, stream>>>((const float4*)Eu0, NU * DD / 4, (uint32_t*)E0u8,
                                            (const float4*)Ev0, NI * DD / 4, (uint32_t*)E0v8);
  (void)hipMemsetAsync(cntU, 0, (size_t)(NU + NI) * sizeof(int), stream);
  mask_hist_kernel<<<(NE / 2 + 255) / 256, 256, 0, stream>>>(rows, cols, mask8, cntU, cntI, K);
  {
    int* bs = (int*)cpU;
    scan_phase1<<<nbU + nbI, SCAN_B, 0, stream>>>(cntU, cntI, nbU, bs);
    scan_phase2<<<1, 512, 0, stream>>>(bs, nbU, nbI);
    scan_phase3<<<nbU + nbI, SCAN_B, 0, stream>>>(cntU, cntI, nbU, bs, offU, offI);
  }
  (void)hipMemsetAsync(cntU, 0, (size_t)(NU + NI) * sizeof(int), stream);
  scatter_kernel<<<NCHUNK * NSLICE, 256, 0, stream>>>(rows, cols, mask8, offU, offI,
                                                      cntU, cntI, cpU, cpI);

  const int SPB = (NU + NI) / 16;   // 4 rows/wave, 4 waves/block -> 9375 blocks

  // ---- propagation 0 (mask bits 17/18) -> E16u/E16i (+fp8 sums) ----
  spmm_layer_kernel<<<SPB, 256, 0, stream>>>(offU, cpU, offI, cpI, av, 17,
                                             E0v8, E0u8, d8U, d8I,
                                             E16u, E16i, Eu0, Ev0, nullptr, nullptr);
  spmm_layer_kernel<<<SPB, 256, 0, stream>>>(offU, cpU, offI, cpI, av, 18,
                                             d8I, d8U, nullptr, nullptr,
                                             E16u, E16i, nullptr, nullptr, E8su, E8si);

  edge_logit_kernel<<<4096, 256, 0, stream>>>(E8su, E8si, rows, cols, av, augv);

  // ---- propagation 1 (mask bits 19/20) -> Z16u/Z16i ----
  spmm_layer_kernel<<<SPB, 256, 0, stream>>>(offU, cpU, offI, cpI, augv, 19,
                                             E0v8, E0u8, d8U, d8I,
                                             Z16u, Z16i, Eu0, Ev0, nullptr, nullptr);
  spmm_layer_kernel<<<SPB, 256, 0, stream>>>(offU, cpU, offI, cpI, augv, 20,
                                             d8I, d8U, nullptr, nullptr,
                                             Z16u, Z16i, nullptr, nullptr, nullptr, nullptr);

  gather2_rows_kernel<<<2 * BATCH, 64, 0, stream>>>(Z16u, uids, Zgu, Z16i, iids, Zgi);

  (void)hipMemsetAsync(Su, 0, (2 * BATCH + 16) * sizeof(float), stream);

  bpr_kernel<<<BATCH / 4, 256, 0, stream>>>(E16u, E16i, uids, pos, neg, ps, acc);
  minmax_kernel<<<1, 256, 0, stream>>>(ps, mm);
  bcl_kernel<<<BATCH / 4, 256, 0, stream>>>(E16u, E16i, Eb, uids, pos, ps, mm, acc);

  // PCL denominators: 4 m-tiles/wave, y=8; x=SPL=128 -> 1024 blocks (4/CU,
  // one residency round), ~49/24 iters per block
  pcl_mfma5_kernel<<<dim3(128, 8), 256, 0, stream>>>(Zgu, E16u, NU / 16, 128, Su);
  pcl_mfma5_kernel<<<dim3(128, 8), 256, 0, stream>>>(Zgi, E16i, NI / 16, 128, Si);

  pclpos2_kernel<<<2 * BATCH / 4, 256, 0, stream>>>(Z16u, E16u, uids, Z16i, E16i, iids, acc);

  sumsq3_kernel<<<1024, 256, 0, stream>>>(Eu0, NU * DD, Ev0, NI * DD, Eb, NBK * DD, acc);

  finalize_kernel<<<1, 256, 0, stream>>>(Su, Si, acc, out);
}